// Round 14
// baseline (1534.845 us; speedup 1.0000x reference)
//
#include <hip/hip_runtime.h>
#include <float.h>
#include <limits.h>

#define NROWS 16384
#define NE    8192
#define DIM   512

// ---- fast pass geometry ----
#define TMF 64
#define TNF 128
#define NSPLITF 4
#define NRANGE (NE / NSPLITF)   // 2048

// ---- refine geometry ----
#define RPB 8
#define NSR 8

// ---- packed-key constants ----
#define KBASE 0x41BE0000u       // bits(23.75f); G+24 in [23.95,24.05] in binade [16,32)
#define KULP  1.9073486e-6f     // ulp in [16,32)

// ---- workspace layout (bytes); control region < 1 MB (EH at 1 MB) ----
#define WS_PKEY 0               // u32[NROWS*NSPLITF*3] = 786432 (top-3 keys/split)
#define WS_FIDX 786432          // int[NROWS]
#define WS_PAIR 851968          // int[NROWS]  pair row ids
#define WS_DEEP 917504          // int[NROWS]  deep row ids
#define WS_CNT  983040          // int[2]: pairCnt, deepCnt
#define WS_EH   1048576         // ushort[NE*DIM] = 8 MB (dead after k_fastm)
#define WS_EL   9437184         // ushort[NE*DIM] = 8 MB
#define WS_RD   1048576         // float[deepCnt*NSR] overlays EH
#define WS_RN   1572864         // int[...]

typedef __bf16 bf16x8 __attribute__((ext_vector_type(8)));
typedef unsigned short u16x8 __attribute__((ext_vector_type(8)));
typedef float f32x4v __attribute__((ext_vector_type(4)));

__device__ __forceinline__ unsigned int bf16rne(float f) {
  unsigned int u = __float_as_uint(f);
  return (u + 0x7FFFu + ((u >> 16) & 1u)) >> 16;
}
__device__ __forceinline__ void split2(float f, unsigned short& h, unsigned short& l) {
  unsigned int hb = bf16rne(f);
  h = (unsigned short)hb;
  float rem = f - __uint_as_float(hb << 16);
  l = (unsigned short)bf16rne(rem);
}

typedef __attribute__((address_space(1))) const void GV;
typedef __attribute__((address_space(3))) void LV;
__device__ __forceinline__ void gload16(const void* g, void* l) {
  __builtin_amdgcn_global_load_lds((GV*)g, (LV*)l, 16, 0, 0);
}

// insert key into sorted (a1 >= a2 >= a3) triple
__device__ __forceinline__ void insert3(unsigned& a1, unsigned& a2, unsigned& a3,
                                        unsigned k) {
  if (k > a1)      { a3 = a2; a2 = a1; a1 = k; }
  else if (k > a2) { a3 = a2; a2 = k; }
  else if (k > a3) { a3 = k; }
}

// ---------------- K0: elementwise bf16 hi/lo pre-split ----------------
__global__ void k_presplit(const float* __restrict__ src,
                           unsigned short* __restrict__ hi,
                           unsigned short* __restrict__ lo) {
  size_t i8 = (size_t)blockIdx.x * 256 + threadIdx.x;
  const float4* s4 = (const float4*)src;
  float4 a = s4[i8 * 2], b = s4[i8 * 2 + 1];
  unsigned short h[8], l[8];
  split2(a.x, h[0], l[0]); split2(a.y, h[1], l[1]);
  split2(a.z, h[2], l[2]); split2(a.w, h[3], l[3]);
  split2(b.x, h[4], l[4]); split2(b.y, h[5], l[5]);
  split2(b.z, h[6], l[6]); split2(b.w, h[7], l[7]);
  *(u16x8*)(hi + i8 * 8) = (u16x8){h[0],h[1],h[2],h[3],h[4],h[5],h[6],h[7]};
  *(u16x8*)(lo + i8 * 8) = (u16x8){l[0],l[1],l[2],l[3],l[4],l[5],l[6],l[7]};
}

// ---------------- K1: MFMA GEMM-max; full dbuf, ONE barrier/K-step, keyed top-3 ----
// grid (256,4), block 256 = 4 waves (2m x 2n), wave tile 32x64.
__global__ __launch_bounds__(256, 2) void k_fastm(
    const unsigned short* __restrict__ zh, const unsigned short* __restrict__ zl,
    const unsigned short* __restrict__ eh, const unsigned short* __restrict__ el,
    unsigned* __restrict__ pkey, int* __restrict__ counters) {
  __shared__ unsigned short zbuf[2][2][TMF][32];    // [dbuf][hi,lo]  16 KB
  __shared__ unsigned short ebuf[2][2][TNF][32];    // [dbuf][hi,lo]  32 KB
  __shared__ unsigned rk[TMF][2][3];

  const int t    = threadIdx.x;
  const int lane = t & 63, w = t >> 6;
  const int wm   = w >> 1, wn = w & 1;
  const int lr   = lane & 15, lg = lane >> 4;
  const int mBase  = blockIdx.x * TMF;
  const int nBase0 = blockIdx.y * NRANGE;
  if (blockIdx.x == 0 && blockIdx.y == 0 && t == 0) { counters[0] = 0; counters[1] = 0; }

  // staging lane maps (inverse-swizzled global source, linear LDS dest — rule #21)
  const int srz = (w << 4) + (lane >> 2);
  const unsigned zbase = (unsigned)(mBase + srz) * DIM + (((lane & 3) ^ ((srz >> 1) & 3)) << 3);
  const int sre0 = (w << 5) + (lane >> 2);
  const int sre1 = sre0 + 16;
  const unsigned ebase0 = (unsigned)(nBase0 + sre0) * DIM + (((lane & 3) ^ ((sre0 >> 1) & 3)) << 3);
  const unsigned ebase1 = (unsigned)(nBase0 + sre1) * DIM + (((lane & 3) ^ ((sre1 >> 1) & 3)) << 3);

  unsigned k1[8], k2[8], k3[8];
  #pragma unroll
  for (int s = 0; s < 8; ++s) { k1[s] = 0u; k2[s] = 0u; k3[s] = 0u; }

  // prologue: stage step 0 into buffer 0
  gload16(zh + zbase, &zbuf[0][0][w << 4][0]);
  gload16(zl + zbase, &zbuf[0][1][w << 4][0]);
  gload16(eh + ebase0, &ebuf[0][0][w << 5][0]);
  gload16(eh + ebase1, &ebuf[0][0][(w << 5) + 16][0]);
  gload16(el + ebase0, &ebuf[0][1][w << 5][0]);
  gload16(el + ebase1, &ebuf[0][1][(w << 5) + 16][0]);
  __syncthreads();

  int cur = 0;
  for (int nt = 0; nt < NRANGE / TNF; ++nt) {     // 16 n-tiles
    const int nB = nBase0 + nt * TNF;
    f32x4v acc[2][4];
    #pragma unroll
    for (int mi = 0; mi < 2; ++mi)
      #pragma unroll
      for (int nj = 0; nj < 4; ++nj) acc[mi][nj] = (f32x4v){0.f, 0.f, 0.f, 0.f};

    for (int ks = 0; ks < 16; ++ks) {             // 16 K-steps of 32
      // ---- issue next-step staging into buf[cur^1] (hides under frags+MFMA) ----
      int s = nt * 16 + ks;
      if (s + 1 < 256) {
        int s2 = s + 1;
        unsigned zo = (unsigned)((s2 & 15) << 5);
        unsigned vo = ((unsigned)(s2 >> 4) << 16) | zo;
        gload16(zh + zbase + zo, &zbuf[cur ^ 1][0][w << 4][0]);
        gload16(zl + zbase + zo, &zbuf[cur ^ 1][1][w << 4][0]);
        gload16(eh + ebase0 + vo, &ebuf[cur ^ 1][0][w << 5][0]);
        gload16(eh + ebase1 + vo, &ebuf[cur ^ 1][0][(w << 5) + 16][0]);
        gload16(el + ebase0 + vo, &ebuf[cur ^ 1][1][w << 5][0]);
        gload16(el + ebase1 + vo, &ebuf[cur ^ 1][1][(w << 5) + 16][0]);
      }
      // ---- a-frags + b-frags + MFMA from buf[cur] (swizzled reads) ----
      bf16x8 ah[2], al[2];
      #pragma unroll
      for (int mi = 0; mi < 2; ++mi) {
        int row = wm * 32 + mi * 16 + lr;
        int sl  = (lg ^ ((row >> 1) & 3)) * 8;
        ah[mi] = *(const bf16x8*)&zbuf[cur][0][row][sl];
        al[mi] = *(const bf16x8*)&zbuf[cur][1][row][sl];
      }
      #pragma unroll
      for (int nj = 0; nj < 4; ++nj) {
        int erow = wn * 64 + nj * 16 + lr;
        int esl  = (lg ^ ((erow >> 1) & 3)) * 8;
        bf16x8 bh = *(const bf16x8*)&ebuf[cur][0][erow][esl];
        bf16x8 bl = *(const bf16x8*)&ebuf[cur][1][erow][esl];
        #pragma unroll
        for (int mi = 0; mi < 2; ++mi) {
          acc[mi][nj] = __builtin_amdgcn_mfma_f32_16x16x32_bf16(ah[mi], bh, acc[mi][nj], 0, 0, 0);
          acc[mi][nj] = __builtin_amdgcn_mfma_f32_16x16x32_bf16(ah[mi], bl, acc[mi][nj], 0, 0, 0);
          acc[mi][nj] = __builtin_amdgcn_mfma_f32_16x16x32_bf16(al[mi], bh, acc[mi][nj], 0, 0, 0);
        }
      }
      __syncthreads();   // single barrier: drains vmcnt (stage) + lgkm (frag reads)
      cur ^= 1;
    }
    // fold: packed-key top-3 per row slot (first-index tie-break embedded)
    #pragma unroll
    for (int nj = 0; nj < 4; ++nj) {
      unsigned nkey = (unsigned)(8191 - (nB + wn * 64 + nj * 16 + lr));
      #pragma unroll
      for (int mi = 0; mi < 2; ++mi)
        #pragma unroll
        for (int r = 0; r < 4; ++r) {
          int s2 = mi * 4 + r;
          float gb = acc[mi][nj][r] + 24.0f;
          int off = (int)(__float_as_uint(gb) - KBASE);
          off = min(max(off, 0), 0x3FFFF);            // clamp-collapse => deep => safe
          unsigned key = ((unsigned)off << 13) | nkey;
          insert3(k1[s2], k2[s2], k3[s2], key);
        }
    }
  }

  // butterfly top-3 merge across the 16 col-lanes
  #pragma unroll
  for (int off = 1; off <= 8; off <<= 1) {
    #pragma unroll
    for (int s = 0; s < 8; ++s) {
      unsigned o1 = __shfl_xor(k1[s], off);
      unsigned o2 = __shfl_xor(k2[s], off);
      unsigned o3 = __shfl_xor(k3[s], off);
      insert3(k1[s], k2[s], k3[s], o1);
      insert3(k1[s], k2[s], k3[s], o2);
      insert3(k1[s], k2[s], k3[s], o3);
    }
  }
  if (lr == 0) {
    #pragma unroll
    for (int s = 0; s < 8; ++s) {
      int row = wm * 32 + (s >> 2) * 16 + lg * 4 + (s & 3);
      rk[row][wn][0] = k1[s]; rk[row][wn][1] = k2[s]; rk[row][wn][2] = k3[s];
    }
  }
  __syncthreads();
  if (t < TMF) {
    unsigned K1 = rk[t][0][0], K2 = rk[t][0][1], K3 = rk[t][0][2];
    insert3(K1, K2, K3, rk[t][1][0]);
    insert3(K1, K2, K3, rk[t][1][1]);
    insert3(K1, K2, K3, rk[t][1][2]);
    size_t gm = ((size_t)(mBase + t) * NSPLITF + blockIdx.y) * 3;
    pkey[gm] = K1; pkey[gm + 1] = K2; pkey[gm + 2] = K3;
  }
}

// ---------------- K2: merge splits, compute A, classify done/pair/deep ----------------
__global__ void k_merge(const float* __restrict__ z, const unsigned* __restrict__ pkey,
                        int* __restrict__ fidx, int* __restrict__ pairL,
                        int* __restrict__ deepL, int* __restrict__ counters) {
  int m = blockIdx.x * 256 + threadIdx.x;
  unsigned K1 = 0, K2 = 0, K3 = 0;
  #pragma unroll
  for (int s = 0; s < NSPLITF; ++s) {
    size_t g = ((size_t)m * NSPLITF + s) * 3;
    insert3(K1, K2, K3, pkey[g]);
    insert3(K1, K2, K3, pkey[g + 1]);
    insert3(K1, K2, K3, pkey[g + 2]);
  }
  double A = 0.0;
  const float4* zr = (const float4*)(z + (size_t)m * DIM);
  for (int q = 0; q < DIM / 4; ++q) {
    float4 v = zr[q];
    A += (double)v.x * v.x + (double)v.y * v.y + (double)v.z * v.z + (double)v.w * v.w;
  }
  float A32 = (float)A;
  float u   = (A32 > 511.8f) ? 6.1035156e-5f : 3.0517578e-5f;
  float tau = 0.75f * u + 7.5e-6f;     // +4e-6 for key bias-rounding (2 ulp(24))
  float gap2 = (float)((K1 >> 13) - (K2 >> 13)) * KULP;   // exact integer diff
  float gap3 = (float)((K1 >> 13) - (K3 >> 13)) * KULP;
  fidx[m] = 8191 - (int)(K1 & 8191u);
  if (gap2 < tau) {
    if (gap3 >= tau + 4.0e-6f) {       // guard: candidates provably {i1,i2}
      int p = atomicAdd(&counters[0], 1);
      pairL[p] = m;
    } else {
      int p = atomicAdd(&counters[1], 1);
      deepL[p] = m;
    }
  }
}

// exact npyv (baseline-SSE) fp32 d for one (z-row, cb-row): verified chain (r2/r3)
__device__ float npyv_d(const float* __restrict__ zr, const float* __restrict__ er,
                        float A32) {
  float L0 = 0.f, L1 = 0.f, L2 = 0.f, L3 = 0.f;
  for (int c = 0; c < 32; ++c) {
    #pragma unroll
    for (int sub = 3; sub >= 0; --sub) {
      int base = c * 16 + sub * 4;
      float4 zv = *(const float4*)(zr + base);
      float4 ev = *(const float4*)(er + base);
      L0 = __fadd_rn(L0, __fmul_rn(zv.x, ev.x));
      L1 = __fadd_rn(L1, __fmul_rn(zv.y, ev.y));
      L2 = __fadd_rn(L2, __fmul_rn(zv.z, ev.z));
      L3 = __fadd_rn(L3, __fmul_rn(zv.w, ev.w));
    }
  }
  float G = __fadd_rn(__fadd_rn(L0, L1), __fadd_rn(L2, L3));
  return __fsub_rn(A32, __fmul_rn(2.0f, G));
}

// ---------------- K3a: pair refine (one thread per flagged-pair row) ----------------
__global__ void k_pair(const float* __restrict__ z, const float* __restrict__ cb,
                       const unsigned* __restrict__ pkey, const int* __restrict__ pairL,
                       const int* __restrict__ counters, int* __restrict__ fidx) {
  int i = blockIdx.x * 256 + threadIdx.x;
  if (i >= counters[0]) return;
  int m = pairL[i];
  unsigned B1 = 0, B2 = 0;                        // global top-2 keys
  #pragma unroll
  for (int s = 0; s < NSPLITF; ++s) {
    size_t g = ((size_t)m * NSPLITF + s) * 3;
    unsigned a = pkey[g], b = pkey[g + 1];
    if (a > B1) { B2 = B1; B1 = a; } else if (a > B2) B2 = a;
    if (b > B1) { B2 = B1; B1 = b; } else if (b > B2) B2 = b;
  }
  int iA = 8191 - (int)(B1 & 8191u);
  int iB = 8191 - (int)(B2 & 8191u);
  const float* zr = z + (size_t)m * DIM;
  double A = 0.0;
  for (int q = 0; q < DIM / 4; ++q) {
    float4 v = *(const float4*)(zr + q * 4);
    A += (double)v.x * v.x + (double)v.y * v.y + (double)v.z * v.z + (double)v.w * v.w;
  }
  float A32 = (float)A;
  float dA = npyv_d(zr, cb + (size_t)iA * DIM, A32);
  float dB = npyv_d(zr, cb + (size_t)iB * DIM, A32);
  fidx[m] = (dB < dA || (dB == dA && iB < iA)) ? iB : iA;
}

// ---------------- K3b: exact npyv full rescan for deep rows ----------------
__global__ __launch_bounds__(256) void k_refine3(
    const float* __restrict__ z, const float* __restrict__ cb,
    const int* __restrict__ deepL, const int* __restrict__ counters,
    float* __restrict__ rd, int* __restrict__ rn) {
  __shared__ float est2[512][20];
  __shared__ __align__(16) float zs2[RPB][516];
  __shared__ double apart[RPB][16];
  __shared__ float Arow[RPB];
  __shared__ int mrow[RPB];
  __shared__ float rdm[RPB][128];
  __shared__ int rnm[RPB][128];

  const int cnt = counters[1];
  const int gB = blockIdx.x * RPB;
  if (gB >= cnt) return;
  const int t = threadIdx.x;
  const int split = blockIdx.y;
  const int nBase0 = split * (NE / NSR);
  const int rg = t >> 7, cg = t & 127;

  if (t < RPB) mrow[t] = deepL[(gB + t < cnt) ? gB + t : cnt - 1];
  __syncthreads();
  #pragma unroll
  for (int i = 0; i < 4; ++i) {
    int li = t + 256 * i; int r = li >> 7, q = li & 127;
    *(float4*)&zs2[r][q * 4] = *(const float4*)(z + (size_t)mrow[r] * DIM + q * 4);
  }
  __syncthreads();
  if (t < 128) {
    int r = t >> 4, seg = t & 15;
    double s = 0.0;
    for (int k = seg * 32; k < seg * 32 + 32; ++k) { double v = zs2[r][k]; s += v * v; }
    apart[r][seg] = s;
  }
  __syncthreads();
  if (t < RPB) { double s = 0.0; for (int c2 = 0; c2 < 16; ++c2) s += apart[t][c2]; Arow[t] = (float)s; }
  __syncthreads();

  float bd[4] = {FLT_MAX, FLT_MAX, FLT_MAX, FLT_MAX};
  int   bn[4] = {INT_MAX, INT_MAX, INT_MAX, INT_MAX};

  for (int tile = 0; tile < 2; ++tile) {
    const int colBase = nBase0 + tile * 512;
    float L[4][4][4];
    #pragma unroll
    for (int r = 0; r < 4; ++r)
      #pragma unroll
      for (int cj = 0; cj < 4; ++cj)
        #pragma unroll
        for (int j = 0; j < 4; ++j) L[r][cj][j] = 0.0f;

    for (int kc = 0; kc < DIM; kc += 16) {
      __syncthreads();
      #pragma unroll
      for (int i = 0; i < 8; ++i) {
        int li = t + 256 * i; int col = li >> 2, q = li & 3;
        float4 v = *(const float4*)(cb + (size_t)(colBase + col) * DIM + kc + 4 * q);
        *(float4*)&est2[col][4 * q] = v;
      }
      __syncthreads();
      #pragma unroll
      for (int sub = 3; sub >= 0; --sub) {
        float4 zv[4], ev[4];
        #pragma unroll
        for (int r = 0; r < 4; ++r)
          zv[r] = *(const float4*)&zs2[rg * 4 + r][kc + 4 * sub];
        #pragma unroll
        for (int cj = 0; cj < 4; ++cj)
          ev[cj] = *(const float4*)&est2[cg + 128 * cj][4 * sub];
        #pragma unroll
        for (int r = 0; r < 4; ++r)
          #pragma unroll
          for (int cj = 0; cj < 4; ++cj) {
            L[r][cj][0] = __fadd_rn(L[r][cj][0], __fmul_rn(zv[r].x, ev[cj].x));
            L[r][cj][1] = __fadd_rn(L[r][cj][1], __fmul_rn(zv[r].y, ev[cj].y));
            L[r][cj][2] = __fadd_rn(L[r][cj][2], __fmul_rn(zv[r].z, ev[cj].z));
            L[r][cj][3] = __fadd_rn(L[r][cj][3], __fmul_rn(zv[r].w, ev[cj].w));
          }
      }
    }
    #pragma unroll
    for (int cj = 0; cj < 4; ++cj)
      #pragma unroll
      for (int r = 0; r < 4; ++r) {
        float G = __fadd_rn(__fadd_rn(L[r][cj][0], L[r][cj][1]),
                            __fadd_rn(L[r][cj][2], L[r][cj][3]));
        float d = __fsub_rn(Arow[rg * 4 + r], __fmul_rn(2.0f, G));
        int n = colBase + cg + 128 * cj;
        if (d < bd[r] || (d == bd[r] && n < bn[r])) { bd[r] = d; bn[r] = n; }
      }
  }
  __syncthreads();
  #pragma unroll
  for (int r = 0; r < 4; ++r) { rdm[rg*4+r][cg] = bd[r]; rnm[rg*4+r][cg] = bn[r]; }
  __syncthreads();
  if (t < RPB && gB + t < cnt) {
    float fb = FLT_MAX; int fn = INT_MAX;
    for (int c2 = 0; c2 < 128; ++c2) {
      float d = rdm[t][c2]; int n = rnm[t][c2];
      if (d < fb || (d == fb && n < fn)) { fb = d; fn = n; }
    }
    size_t i = (size_t)(gB + t);
    rd[i * NSR + split] = fb;
    rn[i * NSR + split] = fn;
  }
}

// ---------------- K3c: merge deep splits ----------------
__global__ void k_fmerge(const int* __restrict__ deepL, const int* __restrict__ counters,
                         const float* __restrict__ rd, const int* __restrict__ rn,
                         int* __restrict__ fidx) {
  int i = blockIdx.x * 256 + threadIdx.x;
  if (i >= counters[1]) return;
  int m = deepL[i];
  float fb = FLT_MAX; int fn = INT_MAX;
  #pragma unroll
  for (int s = 0; s < NSR; ++s) {
    float d = rd[(size_t)i * NSR + s]; int n = rn[(size_t)i * NSR + s];
    if (d < fb || (d == fb && n < fn)) { fb = d; fn = n; }
  }
  fidx[m] = fn;
}

// ---------------- K4: gather z_q + index floats (fully rewrites d_out) ----------------
__global__ void k_gather(const float* __restrict__ cb, const int* __restrict__ fidx,
                         float* __restrict__ out) {
  __shared__ int idxs[32];
  const int t = threadIdx.x;
  const int mBase = blockIdx.x * 32;
  if (t < 32) {
    int id = fidx[mBase + t];
    idxs[t] = id;
    out[(size_t)NROWS * DIM + mBase + t] = (float)id;
  }
  __syncthreads();
  #pragma unroll
  for (int i = 0; i < 16; ++i) {
    int li = t + i * 256, r = li >> 7, q = li & 127;
    *(float4*)(out + (size_t)(mBase + r) * DIM + q * 4) =
        *(const float4*)(cb + (size_t)idxs[r] * DIM + q * 4);
  }
}

extern "C" void kernel_launch(void* const* d_in, const int* in_sizes, int n_in,
                              void* d_out, int out_size, void* d_ws, size_t ws_size,
                              hipStream_t stream) {
  const float* z  = (const float*)d_in[0];
  const float* cb = (const float*)d_in[1];
  float* out = (float*)d_out;
  char* ws = (char*)d_ws;
  unsigned* pkey  = (unsigned*)(ws + WS_PKEY);
  int*      fidx  = (int*)(ws + WS_FIDX);
  int*      pairL = (int*)(ws + WS_PAIR);
  int*      deepL = (int*)(ws + WS_DEEP);
  int*      cnts  = (int*)(ws + WS_CNT);
  float*    rdp   = (float*)(ws + WS_RD);   // overlays EH (dead after k_fastm)
  int*      rnp   = (int*)(ws + WS_RN);

  // z hi/lo pre-split lives in d_out; k_gather fully rewrites d_out afterward.
  unsigned short* zh = (unsigned short*)d_out;
  unsigned short* zl = zh + (size_t)NROWS * DIM;
  unsigned short* eh = (unsigned short*)(ws + WS_EH);
  unsigned short* el = (unsigned short*)(ws + WS_EL);

  hipLaunchKernelGGL(k_presplit, dim3(NROWS * DIM / (256 * 8)), dim3(256), 0, stream,
                     z, zh, zl);
  hipLaunchKernelGGL(k_presplit, dim3(NE * DIM / (256 * 8)), dim3(256), 0, stream,
                     cb, eh, el);
  hipLaunchKernelGGL(k_fastm,   dim3(NROWS / TMF, NSPLITF), dim3(256), 0, stream,
                     zh, zl, eh, el, pkey, cnts);
  hipLaunchKernelGGL(k_merge,   dim3(NROWS / 256), dim3(256), 0, stream,
                     z, pkey, fidx, pairL, deepL, cnts);
  hipLaunchKernelGGL(k_pair,    dim3(NROWS / 256), dim3(256), 0, stream,
                     z, cb, pkey, pairL, cnts, fidx);
  hipLaunchKernelGGL(k_refine3, dim3(NROWS / RPB, NSR), dim3(256), 0, stream,
                     z, cb, deepL, cnts, rdp, rnp);
  hipLaunchKernelGGL(k_fmerge,  dim3(NROWS / 256), dim3(256), 0, stream,
                     deepL, cnts, rdp, rnp, fidx);
  hipLaunchKernelGGL(k_gather,  dim3(NROWS / 32), dim3(256), 0, stream,
                     cb, fidx, out);
}

// Round 15
// 1510.886 us; speedup vs baseline: 1.0159x; 1.0159x over previous
//
#include <hip/hip_runtime.h>
#include <float.h>
#include <limits.h>

#define NROWS 16384
#define NE    8192
#define DIM   512

// ---- fast pass geometry (r13 proven structure) ----
#define TMF 64
#define TNF 128
#define NSPLITF 4
#define NRANGE (NE / NSPLITF)   // 2048

// ---- refine geometry ----
#define RPB 8
#define NSR 8

// ---- packed-key constants ----
#define KBASE 0x41BE0000u       // bits(23.75f); G+24 in [23.95,24.05] in binade [16,32)
#define KULP  1.9073486e-6f     // ulp in [16,32)

// ---- workspace layout (bytes); control region < 1 MB (EH at 1 MB) ----
#define WS_PKEY 0               // u32[NROWS*NSPLITF*3] = 786432 (top-3 keys/split)
#define WS_FIDX 786432          // int[NROWS]
#define WS_PAIR 851968          // int[NROWS]  pair row ids
#define WS_DEEP 917504          // int[NROWS]  deep row ids
#define WS_CNT  983040          // int[2]: pairCnt, deepCnt
#define WS_EH   1048576         // ushort[NE*DIM] = 8 MB (dead after k_fastm)
#define WS_EL   9437184         // ushort[NE*DIM] = 8 MB
#define WS_RD   1048576         // float[deepCnt*NSR] overlays EH
#define WS_RN   1572864         // int[...]

typedef __bf16 bf16x8 __attribute__((ext_vector_type(8)));
typedef unsigned short u16x8 __attribute__((ext_vector_type(8)));
typedef float f32x4v __attribute__((ext_vector_type(4)));

__device__ __forceinline__ unsigned int bf16rne(float f) {
  unsigned int u = __float_as_uint(f);
  return (u + 0x7FFFu + ((u >> 16) & 1u)) >> 16;
}
__device__ __forceinline__ void split2(float f, unsigned short& h, unsigned short& l) {
  unsigned int hb = bf16rne(f);
  h = (unsigned short)hb;
  float rem = f - __uint_as_float(hb << 16);
  l = (unsigned short)bf16rne(rem);
}

typedef __attribute__((address_space(1))) const void GV;
typedef __attribute__((address_space(3))) void LV;
__device__ __forceinline__ void gload16(const void* g, void* l) {
  __builtin_amdgcn_global_load_lds((GV*)g, (LV*)l, 16, 0, 0);
}

// insert key into sorted (a1 >= a2 >= a3) triple — exact total order, 1-op compares
__device__ __forceinline__ void insert3(unsigned& a1, unsigned& a2, unsigned& a3,
                                        unsigned k) {
  if (k > a1)      { a3 = a2; a2 = a1; a1 = k; }
  else if (k > a2) { a3 = a2; a2 = k; }
  else if (k > a3) { a3 = k; }
}

// ---------------- K0: elementwise bf16 hi/lo pre-split ----------------
__global__ void k_presplit(const float* __restrict__ src,
                           unsigned short* __restrict__ hi,
                           unsigned short* __restrict__ lo) {
  size_t i8 = (size_t)blockIdx.x * 256 + threadIdx.x;
  const float4* s4 = (const float4*)src;
  float4 a = s4[i8 * 2], b = s4[i8 * 2 + 1];
  unsigned short h[8], l[8];
  split2(a.x, h[0], l[0]); split2(a.y, h[1], l[1]);
  split2(a.z, h[2], l[2]); split2(a.w, h[3], l[3]);
  split2(b.x, h[4], l[4]); split2(b.y, h[5], l[5]);
  split2(b.z, h[6], l[6]); split2(b.w, h[7], l[7]);
  *(u16x8*)(hi + i8 * 8) = (u16x8){h[0],h[1],h[2],h[3],h[4],h[5],h[6],h[7]};
  *(u16x8*)(lo + i8 * 8) = (u16x8){l[0],l[1],l[2],l[3],l[4],l[5],l[6],l[7]};
}

// ---------------- K1: MFMA GEMM-max (r13 two-barrier structure) + keyed top-3 ----
// grid (256,4), block 256 = 4 waves (2m x 2n), wave tile 32x64.
// z single-buffered (8 KB), e double-buffered (32 KB). Running-pointer staging.
__global__ __launch_bounds__(256, 2) void k_fastm(
    const unsigned short* __restrict__ zh, const unsigned short* __restrict__ zl,
    const unsigned short* __restrict__ eh, const unsigned short* __restrict__ el,
    unsigned* __restrict__ pkey, int* __restrict__ counters) {
  __shared__ unsigned short zbuf[2][TMF][32];       // [hi,lo][row][k]   8 KB single
  __shared__ unsigned short ebuf[2][2][TNF][32];    // [dbuf][hi,lo]    32 KB
  __shared__ unsigned rk[TMF][2][3];

  const int t    = threadIdx.x;
  const int lane = t & 63, w = t >> 6;
  const int wm   = w >> 1, wn = w & 1;
  const int lr   = lane & 15, lg = lane >> 4;
  const int mBase  = blockIdx.x * TMF;
  const int nBase0 = blockIdx.y * NRANGE;
  if (blockIdx.x == 0 && blockIdx.y == 0 && t == 0) { counters[0] = 0; counters[1] = 0; }

  // staging lane maps (inverse-swizzled global source, linear LDS dest — rule #21)
  const int srz = (w << 4) + (lane >> 2);
  const unsigned zbase = (unsigned)(mBase + srz) * DIM + (((lane & 3) ^ ((srz >> 1) & 3)) << 3);
  const int sre0 = (w << 5) + (lane >> 2);
  const int sre1 = sre0 + 16;
  const unsigned ebase0 = (unsigned)(nBase0 + sre0) * DIM + (((lane & 3) ^ ((sre0 >> 1) & 3)) << 3);
  const unsigned ebase1 = (unsigned)(nBase0 + sre1) * DIM + (((lane & 3) ^ ((sre1 >> 1) & 3)) << 3);

  // running staging pointers (advance by +32, wrap adjustments at tile boundaries)
  const unsigned short* zhp = zh + zbase;
  const unsigned short* zlp = zl + zbase;
  const unsigned short* ehp0 = eh + ebase0;
  const unsigned short* ehp1 = eh + ebase1;
  const unsigned short* elp0 = el + ebase0;
  const unsigned short* elp1 = el + ebase1;

  unsigned k1[8], k2[8], k3[8];
  #pragma unroll
  for (int s = 0; s < 8; ++s) { k1[s] = 0u; k2[s] = 0u; k3[s] = 0u; }

  // prologue: stage step 0
  gload16(zhp, &zbuf[0][w << 4][0]);
  gload16(zlp, &zbuf[1][w << 4][0]);
  gload16(ehp0, &ebuf[0][0][w << 5][0]);
  gload16(ehp1, &ebuf[0][0][(w << 5) + 16][0]);
  gload16(elp0, &ebuf[0][1][w << 5][0]);
  gload16(elp1, &ebuf[0][1][(w << 5) + 16][0]);
  __syncthreads();

  int cur = 0;
  for (int nt = 0; nt < NRANGE / TNF; ++nt) {     // 16 n-tiles
    const int nB = nBase0 + nt * TNF;
    f32x4v acc[2][4];
    #pragma unroll
    for (int mi = 0; mi < 2; ++mi)
      #pragma unroll
      for (int nj = 0; nj < 4; ++nj) acc[mi][nj] = (f32x4v){0.f, 0.f, 0.f, 0.f};

    for (int ks = 0; ks < 16; ++ks) {             // 16 K-steps of 32
      // ---- a-frags from zbuf (swizzled reads) ----
      bf16x8 ah[2], al[2];
      #pragma unroll
      for (int mi = 0; mi < 2; ++mi) {
        int row = wm * 32 + mi * 16 + lr;
        int sl  = (lg ^ ((row >> 1) & 3)) * 8;
        ah[mi] = *(const bf16x8*)&zbuf[0][row][sl];
        al[mi] = *(const bf16x8*)&zbuf[1][row][sl];
      }
      __syncthreads();   // A: a-frag reads retired; zbuf safe to overwrite

      // ---- stage next step (async; hides under MFMA) — running pointers ----
      int s = nt * 16 + ks;
      if (s + 1 < 256) {
        bool wrap = ((s + 1) & 15) == 0;
        int dz = wrap ? -480 : 32;                // z: ks2*32 pattern
        int de = wrap ? 65056 : 32;               // e: nt2*65536 + ks2*32 pattern
        zhp += dz; zlp += dz;
        ehp0 += de; ehp1 += de; elp0 += de; elp1 += de;
        gload16(zhp, &zbuf[0][w << 4][0]);
        gload16(zlp, &zbuf[1][w << 4][0]);
        gload16(ehp0, &ebuf[cur ^ 1][0][w << 5][0]);
        gload16(ehp1, &ebuf[cur ^ 1][0][(w << 5) + 16][0]);
        gload16(elp0, &ebuf[cur ^ 1][1][w << 5][0]);
        gload16(elp1, &ebuf[cur ^ 1][1][(w << 5) + 16][0]);
      }

      // ---- b-frags + MFMA from ebuf[cur] ----
      #pragma unroll
      for (int nj = 0; nj < 4; ++nj) {
        int erow = wn * 64 + nj * 16 + lr;
        int esl  = (lg ^ ((erow >> 1) & 3)) * 8;
        bf16x8 bh = *(const bf16x8*)&ebuf[cur][0][erow][esl];
        bf16x8 bl = *(const bf16x8*)&ebuf[cur][1][erow][esl];
        #pragma unroll
        for (int mi = 0; mi < 2; ++mi) {
          acc[mi][nj] = __builtin_amdgcn_mfma_f32_16x16x32_bf16(ah[mi], bh, acc[mi][nj], 0, 0, 0);
          acc[mi][nj] = __builtin_amdgcn_mfma_f32_16x16x32_bf16(ah[mi], bl, acc[mi][nj], 0, 0, 0);
          acc[mi][nj] = __builtin_amdgcn_mfma_f32_16x16x32_bf16(al[mi], bh, acc[mi][nj], 0, 0, 0);
        }
      }
      __syncthreads();   // B: drains vmcnt (stages landed) + lgkm (b reads done)
      cur ^= 1;
    }
    // fold: packed-key top-3 (monotone order embedding, first-index tie-break)
    #pragma unroll
    for (int nj = 0; nj < 4; ++nj) {
      unsigned nkey = (unsigned)(8191 - (nB + wn * 64 + nj * 16 + lr));
      #pragma unroll
      for (int mi = 0; mi < 2; ++mi)
        #pragma unroll
        for (int r = 0; r < 4; ++r) {
          int s2 = mi * 4 + r;
          float gb = acc[mi][nj][r] + 24.0f;
          int off = (int)(__float_as_uint(gb) - KBASE);
          off = min(max(off, 0), 0x3FFFF);        // clamp-collapse => deep => safe
          unsigned key = ((unsigned)off << 13) | nkey;
          insert3(k1[s2], k2[s2], k3[s2], key);
        }
    }
  }

  // butterfly top-3 merge across the 16 col-lanes
  #pragma unroll
  for (int off = 1; off <= 8; off <<= 1) {
    #pragma unroll
    for (int s = 0; s < 8; ++s) {
      unsigned o1 = __shfl_xor(k1[s], off);
      unsigned o2 = __shfl_xor(k2[s], off);
      unsigned o3 = __shfl_xor(k3[s], off);
      insert3(k1[s], k2[s], k3[s], o1);
      insert3(k1[s], k2[s], k3[s], o2);
      insert3(k1[s], k2[s], k3[s], o3);
    }
  }
  if (lr == 0) {
    #pragma unroll
    for (int s = 0; s < 8; ++s) {
      int row = wm * 32 + (s >> 2) * 16 + lg * 4 + (s & 3);
      rk[row][wn][0] = k1[s]; rk[row][wn][1] = k2[s]; rk[row][wn][2] = k3[s];
    }
  }
  __syncthreads();
  if (t < TMF) {
    unsigned K1 = rk[t][0][0], K2 = rk[t][0][1], K3 = rk[t][0][2];
    insert3(K1, K2, K3, rk[t][1][0]);
    insert3(K1, K2, K3, rk[t][1][1]);
    insert3(K1, K2, K3, rk[t][1][2]);
    size_t gm = ((size_t)(mBase + t) * NSPLITF + blockIdx.y) * 3;
    pkey[gm] = K1; pkey[gm + 1] = K2; pkey[gm + 2] = K3;
  }
}

// ---------------- K2: merge splits, compute A, classify done/pair/deep ----------------
__global__ void k_merge(const float* __restrict__ z, const unsigned* __restrict__ pkey,
                        int* __restrict__ fidx, int* __restrict__ pairL,
                        int* __restrict__ deepL, int* __restrict__ counters) {
  int m = blockIdx.x * 256 + threadIdx.x;
  unsigned K1 = 0, K2 = 0, K3 = 0;
  #pragma unroll
  for (int s = 0; s < NSPLITF; ++s) {
    size_t g = ((size_t)m * NSPLITF + s) * 3;
    insert3(K1, K2, K3, pkey[g]);
    insert3(K1, K2, K3, pkey[g + 1]);
    insert3(K1, K2, K3, pkey[g + 2]);
  }
  double A = 0.0;
  const float4* zr = (const float4*)(z + (size_t)m * DIM);
  for (int q = 0; q < DIM / 4; ++q) {
    float4 v = zr[q];
    A += (double)v.x * v.x + (double)v.y * v.y + (double)v.z * v.z + (double)v.w * v.w;
  }
  float A32 = (float)A;
  float u   = (A32 > 511.8f) ? 6.1035156e-5f : 3.0517578e-5f;
  float tau = 0.75f * u + 7.5e-6f;     // +4e-6 for key bias-rounding (2 ulp(24))
  float gap2 = (float)((K1 >> 13) - (K2 >> 13)) * KULP;   // exact integer diff
  float gap3 = (float)((K1 >> 13) - (K3 >> 13)) * KULP;
  fidx[m] = 8191 - (int)(K1 & 8191u);
  if (gap2 < tau) {
    if (gap3 >= tau + 4.0e-6f) {       // guard: candidates provably {i1,i2}
      int p = atomicAdd(&counters[0], 1);
      pairL[p] = m;
    } else {
      int p = atomicAdd(&counters[1], 1);
      deepL[p] = m;
    }
  }
}

// exact npyv (baseline-SSE) fp32 d for one (z-row, cb-row): verified chain (r2/r3)
__device__ float npyv_d(const float* __restrict__ zr, const float* __restrict__ er,
                        float A32) {
  float L0 = 0.f, L1 = 0.f, L2 = 0.f, L3 = 0.f;
  for (int c = 0; c < 32; ++c) {
    #pragma unroll
    for (int sub = 3; sub >= 0; --sub) {
      int base = c * 16 + sub * 4;
      float4 zv = *(const float4*)(zr + base);
      float4 ev = *(const float4*)(er + base);
      L0 = __fadd_rn(L0, __fmul_rn(zv.x, ev.x));
      L1 = __fadd_rn(L1, __fmul_rn(zv.y, ev.y));
      L2 = __fadd_rn(L2, __fmul_rn(zv.z, ev.z));
      L3 = __fadd_rn(L3, __fmul_rn(zv.w, ev.w));
    }
  }
  float G = __fadd_rn(__fadd_rn(L0, L1), __fadd_rn(L2, L3));
  return __fsub_rn(A32, __fmul_rn(2.0f, G));
}

// ---------------- K3a: pair refine (one thread per flagged-pair row) ----------------
__global__ void k_pair(const float* __restrict__ z, const float* __restrict__ cb,
                       const unsigned* __restrict__ pkey, const int* __restrict__ pairL,
                       const int* __restrict__ counters, int* __restrict__ fidx) {
  int i = blockIdx.x * 256 + threadIdx.x;
  if (i >= counters[0]) return;
  int m = pairL[i];
  unsigned B1 = 0, B2 = 0;                        // global top-2 keys
  #pragma unroll
  for (int s = 0; s < NSPLITF; ++s) {
    size_t g = ((size_t)m * NSPLITF + s) * 3;
    unsigned a = pkey[g], b = pkey[g + 1];
    if (a > B1) { B2 = B1; B1 = a; } else if (a > B2) B2 = a;
    if (b > B1) { B2 = B1; B1 = b; } else if (b > B2) B2 = b;
  }
  int iA = 8191 - (int)(B1 & 8191u);
  int iB = 8191 - (int)(B2 & 8191u);
  const float* zr = z + (size_t)m * DIM;
  double A = 0.0;
  for (int q = 0; q < DIM / 4; ++q) {
    float4 v = *(const float4*)(zr + q * 4);
    A += (double)v.x * v.x + (double)v.y * v.y + (double)v.z * v.z + (double)v.w * v.w;
  }
  float A32 = (float)A;
  float dA = npyv_d(zr, cb + (size_t)iA * DIM, A32);
  float dB = npyv_d(zr, cb + (size_t)iB * DIM, A32);
  fidx[m] = (dB < dA || (dB == dA && iB < iA)) ? iB : iA;
}

// ---------------- K3b: exact npyv full rescan for deep rows ----------------
__global__ __launch_bounds__(256) void k_refine3(
    const float* __restrict__ z, const float* __restrict__ cb,
    const int* __restrict__ deepL, const int* __restrict__ counters,
    float* __restrict__ rd, int* __restrict__ rn) {
  __shared__ float est2[512][20];
  __shared__ __align__(16) float zs2[RPB][516];
  __shared__ double apart[RPB][16];
  __shared__ float Arow[RPB];
  __shared__ int mrow[RPB];
  __shared__ float rdm[RPB][128];
  __shared__ int rnm[RPB][128];

  const int cnt = counters[1];
  const int gB = blockIdx.x * RPB;
  if (gB >= cnt) return;
  const int t = threadIdx.x;
  const int split = blockIdx.y;
  const int nBase0 = split * (NE / NSR);
  const int rg = t >> 7, cg = t & 127;

  if (t < RPB) mrow[t] = deepL[(gB + t < cnt) ? gB + t : cnt - 1];
  __syncthreads();
  #pragma unroll
  for (int i = 0; i < 4; ++i) {
    int li = t + 256 * i; int r = li >> 7, q = li & 127;
    *(float4*)&zs2[r][q * 4] = *(const float4*)(z + (size_t)mrow[r] * DIM + q * 4);
  }
  __syncthreads();
  if (t < 128) {
    int r = t >> 4, seg = t & 15;
    double s = 0.0;
    for (int k = seg * 32; k < seg * 32 + 32; ++k) { double v = zs2[r][k]; s += v * v; }
    apart[r][seg] = s;
  }
  __syncthreads();
  if (t < RPB) { double s = 0.0; for (int c2 = 0; c2 < 16; ++c2) s += apart[t][c2]; Arow[t] = (float)s; }
  __syncthreads();

  float bd[4] = {FLT_MAX, FLT_MAX, FLT_MAX, FLT_MAX};
  int   bn[4] = {INT_MAX, INT_MAX, INT_MAX, INT_MAX};

  for (int tile = 0; tile < 2; ++tile) {
    const int colBase = nBase0 + tile * 512;
    float L[4][4][4];
    #pragma unroll
    for (int r = 0; r < 4; ++r)
      #pragma unroll
      for (int cj = 0; cj < 4; ++cj)
        #pragma unroll
        for (int j = 0; j < 4; ++j) L[r][cj][j] = 0.0f;

    for (int kc = 0; kc < DIM; kc += 16) {
      __syncthreads();
      #pragma unroll
      for (int i = 0; i < 8; ++i) {
        int li = t + 256 * i; int col = li >> 2, q = li & 3;
        float4 v = *(const float4*)(cb + (size_t)(colBase + col) * DIM + kc + 4 * q);
        *(float4*)&est2[col][4 * q] = v;
      }
      __syncthreads();
      #pragma unroll
      for (int sub = 3; sub >= 0; --sub) {
        float4 zv[4], ev[4];
        #pragma unroll
        for (int r = 0; r < 4; ++r)
          zv[r] = *(const float4*)&zs2[rg * 4 + r][kc + 4 * sub];
        #pragma unroll
        for (int cj = 0; cj < 4; ++cj)
          ev[cj] = *(const float4*)&est2[cg + 128 * cj][4 * sub];
        #pragma unroll
        for (int r = 0; r < 4; ++r)
          #pragma unroll
          for (int cj = 0; cj < 4; ++cj) {
            L[r][cj][0] = __fadd_rn(L[r][cj][0], __fmul_rn(zv[r].x, ev[cj].x));
            L[r][cj][1] = __fadd_rn(L[r][cj][1], __fmul_rn(zv[r].y, ev[cj].y));
            L[r][cj][2] = __fadd_rn(L[r][cj][2], __fmul_rn(zv[r].z, ev[cj].z));
            L[r][cj][3] = __fadd_rn(L[r][cj][3], __fmul_rn(zv[r].w, ev[cj].w));
          }
      }
    }
    #pragma unroll
    for (int cj = 0; cj < 4; ++cj)
      #pragma unroll
      for (int r = 0; r < 4; ++r) {
        float G = __fadd_rn(__fadd_rn(L[r][cj][0], L[r][cj][1]),
                            __fadd_rn(L[r][cj][2], L[r][cj][3]));
        float d = __fsub_rn(Arow[rg * 4 + r], __fmul_rn(2.0f, G));
        int n = colBase + cg + 128 * cj;
        if (d < bd[r] || (d == bd[r] && n < bn[r])) { bd[r] = d; bn[r] = n; }
      }
  }
  __syncthreads();
  #pragma unroll
  for (int r = 0; r < 4; ++r) { rdm[rg*4+r][cg] = bd[r]; rnm[rg*4+r][cg] = bn[r]; }
  __syncthreads();
  if (t < RPB && gB + t < cnt) {
    float fb = FLT_MAX; int fn = INT_MAX;
    for (int c2 = 0; c2 < 128; ++c2) {
      float d = rdm[t][c2]; int n = rnm[t][c2];
      if (d < fb || (d == fb && n < fn)) { fb = d; fn = n; }
    }
    size_t i = (size_t)(gB + t);
    rd[i * NSR + split] = fb;
    rn[i * NSR + split] = fn;
  }
}

// ---------------- K3c: merge deep splits ----------------
__global__ void k_fmerge(const int* __restrict__ deepL, const int* __restrict__ counters,
                         const float* __restrict__ rd, const int* __restrict__ rn,
                         int* __restrict__ fidx) {
  int i = blockIdx.x * 256 + threadIdx.x;
  if (i >= counters[1]) return;
  int m = deepL[i];
  float fb = FLT_MAX; int fn = INT_MAX;
  #pragma unroll
  for (int s = 0; s < NSR; ++s) {
    float d = rd[(size_t)i * NSR + s]; int n = rn[(size_t)i * NSR + s];
    if (d < fb || (d == fb && n < fn)) { fb = d; fn = n; }
  }
  fidx[m] = fn;
}

// ---------------- K4: gather z_q + index floats (fully rewrites d_out) ----------------
__global__ void k_gather(const float* __restrict__ cb, const int* __restrict__ fidx,
                         float* __restrict__ out) {
  __shared__ int idxs[32];
  const int t = threadIdx.x;
  const int mBase = blockIdx.x * 32;
  if (t < 32) {
    int id = fidx[mBase + t];
    idxs[t] = id;
    out[(size_t)NROWS * DIM + mBase + t] = (float)id;
  }
  __syncthreads();
  #pragma unroll
  for (int i = 0; i < 16; ++i) {
    int li = t + i * 256, r = li >> 7, q = li & 127;
    *(float4*)(out + (size_t)(mBase + r) * DIM + q * 4) =
        *(const float4*)(cb + (size_t)idxs[r] * DIM + q * 4);
  }
}

extern "C" void kernel_launch(void* const* d_in, const int* in_sizes, int n_in,
                              void* d_out, int out_size, void* d_ws, size_t ws_size,
                              hipStream_t stream) {
  const float* z  = (const float*)d_in[0];
  const float* cb = (const float*)d_in[1];
  float* out = (float*)d_out;
  char* ws = (char*)d_ws;
  unsigned* pkey  = (unsigned*)(ws + WS_PKEY);
  int*      fidx  = (int*)(ws + WS_FIDX);
  int*      pairL = (int*)(ws + WS_PAIR);
  int*      deepL = (int*)(ws + WS_DEEP);
  int*      cnts  = (int*)(ws + WS_CNT);
  float*    rdp   = (float*)(ws + WS_RD);   // overlays EH (dead after k_fastm)
  int*      rnp   = (int*)(ws + WS_RN);

  // z hi/lo pre-split lives in d_out; k_gather fully rewrites d_out afterward.
  unsigned short* zh = (unsigned short*)d_out;
  unsigned short* zl = zh + (size_t)NROWS * DIM;
  unsigned short* eh = (unsigned short*)(ws + WS_EH);
  unsigned short* el = (unsigned short*)(ws + WS_EL);

  hipLaunchKernelGGL(k_presplit, dim3(NROWS * DIM / (256 * 8)), dim3(256), 0, stream,
                     z, zh, zl);
  hipLaunchKernelGGL(k_presplit, dim3(NE * DIM / (256 * 8)), dim3(256), 0, stream,
                     cb, eh, el);
  hipLaunchKernelGGL(k_fastm,   dim3(NROWS / TMF, NSPLITF), dim3(256), 0, stream,
                     zh, zl, eh, el, pkey, cnts);
  hipLaunchKernelGGL(k_merge,   dim3(NROWS / 256), dim3(256), 0, stream,
                     z, pkey, fidx, pairL, deepL, cnts);
  hipLaunchKernelGGL(k_pair,    dim3(NROWS / 256), dim3(256), 0, stream,
                     z, cb, pkey, pairL, cnts, fidx);
  hipLaunchKernelGGL(k_refine3, dim3(NROWS / RPB, NSR), dim3(256), 0, stream,
                     z, cb, deepL, cnts, rdp, rnp);
  hipLaunchKernelGGL(k_fmerge,  dim3(NROWS / 256), dim3(256), 0, stream,
                     deepL, cnts, rdp, rnp, fidx);
  hipLaunchKernelGGL(k_gather,  dim3(NROWS / 32), dim3(256), 0, stream,
                     cb, fidx, out);
}

// Round 16
// 829.129 us; speedup vs baseline: 1.8512x; 1.8223x over previous
//
#include <hip/hip_runtime.h>
#include <float.h>
#include <limits.h>

#define NROWS 16384
#define NE    8192
#define DIM   512

// ---- fast pass geometry ----
#define TMF 64
#define TNF 128
#define NSPLITF 4
#define NRANGE (NE / NSPLITF)   // 2048

// ---- refine geometry ----
#define RPB 8
#define NSR 8

// ---- quantization for stored gaps ----
#define DQSCALE 6.5536e7f       // u16 fixed-point (res 1.526e-8), floored -> conservative
#define DQINV   (1.0f / DQSCALE)

// ---- workspace layout (bytes); control region < 1 MB (EH at 1 MB) ----
#define WS_PM1  0               // float[NROWS*4]   m1 per (row,split)
#define WS_PIX  262144          // u32[NROWS*4]     i1 | i2<<13
#define WS_PDL  524288          // u32[NROWS*4]     dq2 | dq3<<16
#define WS_FIDX 786432          // int[NROWS]
#define WS_PAIR 851968          // int[NROWS]
#define WS_DEEP 917504          // int[NROWS]
#define WS_CNT  983040          // int[2]: pairCnt, deepCnt
#define WS_EH   1048576         // ushort[NE*DIM] = 8 MB (dead after k_fastm)
#define WS_RD   1048576         // float[deepCnt*NSR] overlays EH
#define WS_RN   1572864         // int[...]

typedef __bf16 bf16x8 __attribute__((ext_vector_type(8)));
typedef unsigned short u16x8 __attribute__((ext_vector_type(8)));
typedef float f32x4v __attribute__((ext_vector_type(4)));

__device__ __forceinline__ unsigned int bf16rne(float f) {
  unsigned int u = __float_as_uint(f);
  return (u + 0x7FFFu + ((u >> 16) & 1u)) >> 16;
}

typedef __attribute__((address_space(1))) const void GV;
typedef __attribute__((address_space(3))) void LV;
__device__ __forceinline__ void gload16(const void* g, void* l) {
  __builtin_amdgcn_global_load_lds((GV*)g, (LV*)l, 16, 0, 0);
}

// top-3 set merge (r13 proven): keeps first-index tie-break on m1.
__device__ __forceinline__ void merge3(float& am1, int& ai1, float& am2, int& ai2,
                                       float& am3, float bm1, int bi1, float bm2,
                                       int bi2, float bm3) {
  if (bm1 > am1 || (bm1 == am1 && bi1 < ai1)) {
    float t; int ti;
    t = am1; am1 = bm1; bm1 = t;  ti = ai1; ai1 = bi1; bi1 = ti;
    t = am2; am2 = bm2; bm2 = t;  ti = ai2; ai2 = bi2; bi2 = ti;
    t = am3; am3 = bm3; bm3 = t;
  }
  if (bm1 > am2) { am3 = fmaxf(am2, bm2); am2 = bm1; ai2 = bi1; }
  else           { am3 = fmaxf(am3, bm1); }
}

// ---------------- K0: elementwise bf16 hi-only pre-split ----------------
__global__ void k_presplit_h(const float* __restrict__ src,
                             unsigned short* __restrict__ hi) {
  size_t i8 = (size_t)blockIdx.x * 256 + threadIdx.x;
  const float4* s4 = (const float4*)src;
  float4 a = s4[i8 * 2], b = s4[i8 * 2 + 1];
  *(u16x8*)(hi + i8 * 8) = (u16x8){
      (unsigned short)bf16rne(a.x), (unsigned short)bf16rne(a.y),
      (unsigned short)bf16rne(a.z), (unsigned short)bf16rne(a.w),
      (unsigned short)bf16rne(b.x), (unsigned short)bf16rne(b.y),
      (unsigned short)bf16rne(b.z), (unsigned short)bf16rne(b.w)};
}

// ---------------- K1: 1-term bf16 MFMA GEMM-max + float/index top-3 ----------------
// grid (256,4), block 256 = 4 waves (2m x 2n), wave tile 32x64. r13 two-barrier
// structure; zh-only A, eh-only B (error absorbed by enlarged tau in k_merge).
// LDS 22.5 KB -> 4 blocks/CU.
__global__ __launch_bounds__(256, 2) void k_fastm(
    const unsigned short* __restrict__ zh, const unsigned short* __restrict__ eh,
    float* __restrict__ pm1, unsigned* __restrict__ pix, unsigned* __restrict__ pdl,
    int* __restrict__ counters) {
  __shared__ unsigned short zbuf[TMF][32];          //  4 KB single-buffered
  __shared__ unsigned short ebuf[2][TNF][32];       // 16 KB dbuf
  __shared__ float rm1[TMF][2], rm2[TMF][2], rm3[TMF][2];
  __shared__ int   ri1[TMF][2], ri2[TMF][2];

  const int t    = threadIdx.x;
  const int lane = t & 63, w = t >> 6;
  const int wm   = w >> 1, wn = w & 1;
  const int lr   = lane & 15, lg = lane >> 4;
  const int mBase  = blockIdx.x * TMF;
  const int nBase0 = blockIdx.y * NRANGE;
  if (blockIdx.x == 0 && blockIdx.y == 0 && t == 0) { counters[0] = 0; counters[1] = 0; }

  // staging lane maps (inverse-swizzled global source, linear LDS dest — rule #21)
  const int srz = (w << 4) + (lane >> 2);
  const unsigned zbase = (unsigned)(mBase + srz) * DIM + (((lane & 3) ^ ((srz >> 1) & 3)) << 3);
  const int sre0 = (w << 5) + (lane >> 2);
  const int sre1 = sre0 + 16;
  const unsigned ebase0 = (unsigned)(nBase0 + sre0) * DIM + (((lane & 3) ^ ((sre0 >> 1) & 3)) << 3);
  const unsigned ebase1 = (unsigned)(nBase0 + sre1) * DIM + (((lane & 3) ^ ((sre1 >> 1) & 3)) << 3);

  float m1[8], m2[8], m3[8]; int i1[8], i2[8];
  #pragma unroll
  for (int s = 0; s < 8; ++s) {
    m1[s] = -FLT_MAX; m2[s] = -FLT_MAX; m3[s] = -FLT_MAX;
    i1[s] = INT_MAX;  i2[s] = INT_MAX;
  }

  // prologue: stage step 0
  gload16(zh + zbase, &zbuf[w << 4][0]);
  gload16(eh + ebase0, &ebuf[0][w << 5][0]);
  gload16(eh + ebase1, &ebuf[0][(w << 5) + 16][0]);
  __syncthreads();

  int cur = 0;
  for (int nt = 0; nt < NRANGE / TNF; ++nt) {     // 16 n-tiles
    const int nB = nBase0 + nt * TNF;
    f32x4v acc[2][4];
    #pragma unroll
    for (int mi = 0; mi < 2; ++mi)
      #pragma unroll
      for (int nj = 0; nj < 4; ++nj) acc[mi][nj] = (f32x4v){0.f, 0.f, 0.f, 0.f};

    for (int ks = 0; ks < 16; ++ks) {             // 16 K-steps of 32
      // ---- a-frags from zbuf (swizzled reads) ----
      bf16x8 ah[2];
      #pragma unroll
      for (int mi = 0; mi < 2; ++mi) {
        int row = wm * 32 + mi * 16 + lr;
        int sl  = (lg ^ ((row >> 1) & 3)) * 8;
        ah[mi] = *(const bf16x8*)&zbuf[row][sl];
      }
      __syncthreads();   // A: a-frag reads retired; zbuf safe to overwrite

      // ---- stage next step (async; hides under MFMA) ----
      int s = nt * 16 + ks;
      if (s + 1 < 256) {
        int s2 = s + 1;
        unsigned zo = (unsigned)((s2 & 15) << 5);
        unsigned vo = ((unsigned)(s2 >> 4) << 16) | zo;   // nt2*TNF*DIM + ks2*32
        gload16(zh + zbase + zo, &zbuf[w << 4][0]);
        gload16(eh + ebase0 + vo, &ebuf[cur ^ 1][w << 5][0]);
        gload16(eh + ebase1 + vo, &ebuf[cur ^ 1][(w << 5) + 16][0]);
      }

      // ---- b-frags + 8 MFMA from ebuf[cur] ----
      #pragma unroll
      for (int nj = 0; nj < 4; ++nj) {
        int erow = wn * 64 + nj * 16 + lr;
        int esl  = (lg ^ ((erow >> 1) & 3)) * 8;
        bf16x8 bh = *(const bf16x8*)&ebuf[cur][erow][esl];
        #pragma unroll
        for (int mi = 0; mi < 2; ++mi)
          acc[mi][nj] = __builtin_amdgcn_mfma_f32_16x16x32_bf16(ah[mi], bh, acc[mi][nj], 0, 0, 0);
      }
      __syncthreads();   // B: drains vmcnt (stages landed) + lgkm (b reads done)
      cur ^= 1;
    }
    // fold into per-thread top-3 (n ascending -> first index kept)
    #pragma unroll
    for (int nj = 0; nj < 4; ++nj) {
      int n = nB + wn * 64 + nj * 16 + lr;
      #pragma unroll
      for (int mi = 0; mi < 2; ++mi)
        #pragma unroll
        for (int r = 0; r < 4; ++r) {
          float v = acc[mi][nj][r];
          int s = mi * 4 + r;
          if (v > m1[s]) { m3[s] = m2[s]; m2[s] = m1[s]; i2[s] = i1[s]; m1[s] = v; i1[s] = n; }
          else if (v > m2[s]) { m3[s] = m2[s]; m2[s] = v; i2[s] = n; }
          else if (v > m3[s]) { m3[s] = v; }
        }
    }
  }

  // butterfly top-3 merge across the 16 col-lanes
  #pragma unroll
  for (int off = 1; off <= 8; off <<= 1) {
    #pragma unroll
    for (int s = 0; s < 8; ++s) {
      float om1 = __shfl_xor(m1[s], off);
      float om2 = __shfl_xor(m2[s], off);
      float om3 = __shfl_xor(m3[s], off);
      int   oi1 = __shfl_xor(i1[s], off);
      int   oi2 = __shfl_xor(i2[s], off);
      merge3(m1[s], i1[s], m2[s], i2[s], m3[s], om1, oi1, om2, oi2, om3);
    }
  }
  if (lr == 0) {
    #pragma unroll
    for (int s = 0; s < 8; ++s) {
      int row = wm * 32 + (s >> 2) * 16 + lg * 4 + (s & 3);
      rm1[row][wn] = m1[s]; rm2[row][wn] = m2[s]; rm3[row][wn] = m3[s];
      ri1[row][wn] = i1[s]; ri2[row][wn] = i2[s];
    }
  }
  __syncthreads();
  if (t < TMF) {
    float M1 = rm1[t][0], M2 = rm2[t][0], M3 = rm3[t][0];
    int   I1 = ri1[t][0], I2 = ri2[t][0];
    merge3(M1, I1, M2, I2, M3, rm1[t][1], ri1[t][1], rm2[t][1], ri2[t][1], rm3[t][1]);
    size_t gm = (size_t)(mBase + t) * NSPLITF + blockIdx.y;
    unsigned q2 = (unsigned)fminf((M1 - M2) * DQSCALE, 65535.0f);  // floored: underest.
    unsigned q3 = (unsigned)fminf((M1 - M3) * DQSCALE, 65535.0f);
    pm1[gm] = M1;
    pix[gm] = (unsigned)I1 | ((unsigned)I2 << 13);
    pdl[gm] = q2 | (q3 << 16);
  }
}

// ---------------- K2: merge splits, compute A, classify done/pair/deep ----------------
__global__ void k_merge(const float* __restrict__ z,
                        const float* __restrict__ pm1, const unsigned* __restrict__ pix,
                        const unsigned* __restrict__ pdl,
                        int* __restrict__ fidx, int* __restrict__ pairM,
                        unsigned* __restrict__ pairIJ, int* __restrict__ deepL,
                        int* __restrict__ counters) {
  int m = blockIdx.x * 256 + threadIdx.x;
  float M1 = -FLT_MAX, M2 = -FLT_MAX, M3 = -FLT_MAX; int I1 = INT_MAX, I2 = INT_MAX;
  #pragma unroll
  for (int s = 0; s < NSPLITF; ++s) {
    size_t g = (size_t)m * NSPLITF + s;
    float bm1 = pm1[g];
    unsigned ij = pix[g], dq = pdl[g];
    int   bi1 = (int)(ij & 8191u), bi2 = (int)((ij >> 13) & 8191u);
    float bm2 = bm1 - (float)(dq & 0xFFFFu) * DQINV;   // >= true m2 (conservative)
    float bm3 = bm1 - (float)(dq >> 16) * DQINV;
    merge3(M1, I1, M2, I2, M3, bm1, bi1, bm2, bi2, bm3);
  }
  double A = 0.0;
  const float4* zr = (const float4*)(z + (size_t)m * DIM);
  for (int q = 0; q < DIM / 4; ++q) {
    float4 v = zr[q];
    A += (double)v.x * v.x + (double)v.y * v.y + (double)v.z * v.z + (double)v.w * v.w;
  }
  float A32 = (float)A;
  // 1-term fast pass: eta(diff) sigma ~6e-6, Hoeffding tail at 8e-5 ~ 2e-18/pair.
  // unflagged => G-gap_true > 0.5*ulp(d) => ref-exact.
  float u   = (A32 > 511.8f) ? 6.1035156e-5f : 3.0517578e-5f;
  float tau = 0.75f * u + 8.0e-5f;
  fidx[m] = I1;
  if (M1 - M2 < tau) {
    if (M1 - M3 >= tau + 2.0e-5f) {      // guard: candidates provably {I1,I2}
      int p = atomicAdd(&counters[0], 1);
      pairM[p] = m;
      pairIJ[p] = (unsigned)I1 | ((unsigned)I2 << 13);
    } else {
      int p = atomicAdd(&counters[1], 1);
      deepL[p] = m;
    }
  }
}

// exact npyv (baseline-SSE) fp32 d for one (z-row, cb-row): verified chain (r2/r3)
__device__ float npyv_d(const float* __restrict__ zr, const float* __restrict__ er,
                        float A32) {
  float L0 = 0.f, L1 = 0.f, L2 = 0.f, L3 = 0.f;
  for (int c = 0; c < 32; ++c) {
    #pragma unroll
    for (int sub = 3; sub >= 0; --sub) {
      int base = c * 16 + sub * 4;
      float4 zv = *(const float4*)(zr + base);
      float4 ev = *(const float4*)(er + base);
      L0 = __fadd_rn(L0, __fmul_rn(zv.x, ev.x));
      L1 = __fadd_rn(L1, __fmul_rn(zv.y, ev.y));
      L2 = __fadd_rn(L2, __fmul_rn(zv.z, ev.z));
      L3 = __fadd_rn(L3, __fmul_rn(zv.w, ev.w));
    }
  }
  float G = __fadd_rn(__fadd_rn(L0, L1), __fadd_rn(L2, L3));
  return __fsub_rn(A32, __fmul_rn(2.0f, G));
}

// ---------------- K3a: pair refine (one thread per flagged-pair row) ----------------
__global__ void k_pair(const float* __restrict__ z, const float* __restrict__ cb,
                       const int* __restrict__ pairM, const unsigned* __restrict__ pairIJ,
                       const int* __restrict__ counters, int* __restrict__ fidx) {
  int i = blockIdx.x * 256 + threadIdx.x;
  if (i >= counters[0]) return;
  int m = pairM[i];
  unsigned ij = pairIJ[i];
  int iA = (int)(ij & 8191u), iB = (int)((ij >> 13) & 8191u);
  const float* zr = z + (size_t)m * DIM;
  double A = 0.0;
  for (int q = 0; q < DIM / 4; ++q) {
    float4 v = *(const float4*)(zr + q * 4);
    A += (double)v.x * v.x + (double)v.y * v.y + (double)v.z * v.z + (double)v.w * v.w;
  }
  float A32 = (float)A;
  float dA = npyv_d(zr, cb + (size_t)iA * DIM, A32);
  float dB = npyv_d(zr, cb + (size_t)iB * DIM, A32);
  fidx[m] = (dB < dA || (dB == dA && iB < iA)) ? iB : iA;
}

// ---------------- K3b: exact npyv full rescan for deep rows ----------------
__global__ __launch_bounds__(256) void k_refine3(
    const float* __restrict__ z, const float* __restrict__ cb,
    const int* __restrict__ deepL, const int* __restrict__ counters,
    float* __restrict__ rd, int* __restrict__ rn) {
  __shared__ float est2[512][20];
  __shared__ __align__(16) float zs2[RPB][516];
  __shared__ double apart[RPB][16];
  __shared__ float Arow[RPB];
  __shared__ int mrow[RPB];
  __shared__ float rdm[RPB][128];
  __shared__ int rnm[RPB][128];

  const int cnt = counters[1];
  const int gB = blockIdx.x * RPB;
  if (gB >= cnt) return;
  const int t = threadIdx.x;
  const int split = blockIdx.y;
  const int nBase0 = split * (NE / NSR);
  const int rg = t >> 7, cg = t & 127;

  if (t < RPB) mrow[t] = deepL[(gB + t < cnt) ? gB + t : cnt - 1];
  __syncthreads();
  #pragma unroll
  for (int i = 0; i < 4; ++i) {
    int li = t + 256 * i; int r = li >> 7, q = li & 127;
    *(float4*)&zs2[r][q * 4] = *(const float4*)(z + (size_t)mrow[r] * DIM + q * 4);
  }
  __syncthreads();
  if (t < 128) {
    int r = t >> 4, seg = t & 15;
    double s = 0.0;
    for (int k = seg * 32; k < seg * 32 + 32; ++k) { double v = zs2[r][k]; s += v * v; }
    apart[r][seg] = s;
  }
  __syncthreads();
  if (t < RPB) { double s = 0.0; for (int c2 = 0; c2 < 16; ++c2) s += apart[t][c2]; Arow[t] = (float)s; }
  __syncthreads();

  float bd[4] = {FLT_MAX, FLT_MAX, FLT_MAX, FLT_MAX};
  int   bn[4] = {INT_MAX, INT_MAX, INT_MAX, INT_MAX};

  for (int tile = 0; tile < 2; ++tile) {
    const int colBase = nBase0 + tile * 512;
    float L[4][4][4];
    #pragma unroll
    for (int r = 0; r < 4; ++r)
      #pragma unroll
      for (int cj = 0; cj < 4; ++cj)
        #pragma unroll
        for (int j = 0; j < 4; ++j) L[r][cj][j] = 0.0f;

    for (int kc = 0; kc < DIM; kc += 16) {
      __syncthreads();
      #pragma unroll
      for (int i = 0; i < 8; ++i) {
        int li = t + 256 * i; int col = li >> 2, q = li & 3;
        float4 v = *(const float4*)(cb + (size_t)(colBase + col) * DIM + kc + 4 * q);
        *(float4*)&est2[col][4 * q] = v;
      }
      __syncthreads();
      #pragma unroll
      for (int sub = 3; sub >= 0; --sub) {
        float4 zv[4], ev[4];
        #pragma unroll
        for (int r = 0; r < 4; ++r)
          zv[r] = *(const float4*)&zs2[rg * 4 + r][kc + 4 * sub];
        #pragma unroll
        for (int cj = 0; cj < 4; ++cj)
          ev[cj] = *(const float4*)&est2[cg + 128 * cj][4 * sub];
        #pragma unroll
        for (int r = 0; r < 4; ++r)
          #pragma unroll
          for (int cj = 0; cj < 4; ++cj) {
            L[r][cj][0] = __fadd_rn(L[r][cj][0], __fmul_rn(zv[r].x, ev[cj].x));
            L[r][cj][1] = __fadd_rn(L[r][cj][1], __fmul_rn(zv[r].y, ev[cj].y));
            L[r][cj][2] = __fadd_rn(L[r][cj][2], __fmul_rn(zv[r].z, ev[cj].z));
            L[r][cj][3] = __fadd_rn(L[r][cj][3], __fmul_rn(zv[r].w, ev[cj].w));
          }
      }
    }
    #pragma unroll
    for (int cj = 0; cj < 4; ++cj)
      #pragma unroll
      for (int r = 0; r < 4; ++r) {
        float G = __fadd_rn(__fadd_rn(L[r][cj][0], L[r][cj][1]),
                            __fadd_rn(L[r][cj][2], L[r][cj][3]));
        float d = __fsub_rn(Arow[rg * 4 + r], __fmul_rn(2.0f, G));
        int n = colBase + cg + 128 * cj;
        if (d < bd[r] || (d == bd[r] && n < bn[r])) { bd[r] = d; bn[r] = n; }
      }
  }
  __syncthreads();
  #pragma unroll
  for (int r = 0; r < 4; ++r) { rdm[rg*4+r][cg] = bd[r]; rnm[rg*4+r][cg] = bn[r]; }
  __syncthreads();
  if (t < RPB && gB + t < cnt) {
    float fb = FLT_MAX; int fn = INT_MAX;
    for (int c2 = 0; c2 < 128; ++c2) {
      float d = rdm[t][c2]; int n = rnm[t][c2];
      if (d < fb || (d == fb && n < fn)) { fb = d; fn = n; }
    }
    size_t i = (size_t)(gB + t);
    rd[i * NSR + split] = fb;
    rn[i * NSR + split] = fn;
  }
}

// ---------------- K3c: merge deep splits ----------------
__global__ void k_fmerge(const int* __restrict__ deepL, const int* __restrict__ counters,
                         const float* __restrict__ rd, const int* __restrict__ rn,
                         int* __restrict__ fidx) {
  int i = blockIdx.x * 256 + threadIdx.x;
  if (i >= counters[1]) return;
  int m = deepL[i];
  float fb = FLT_MAX; int fn = INT_MAX;
  #pragma unroll
  for (int s = 0; s < NSR; ++s) {
    float d = rd[(size_t)i * NSR + s]; int n = rn[(size_t)i * NSR + s];
    if (d < fb || (d == fb && n < fn)) { fb = d; fn = n; }
  }
  fidx[m] = fn;
}

// ---------------- K4: gather z_q + index floats (fully rewrites d_out) ----------------
__global__ void k_gather(const float* __restrict__ cb, const int* __restrict__ fidx,
                         float* __restrict__ out) {
  __shared__ int idxs[32];
  const int t = threadIdx.x;
  const int mBase = blockIdx.x * 32;
  if (t < 32) {
    int id = fidx[mBase + t];
    idxs[t] = id;
    out[(size_t)NROWS * DIM + mBase + t] = (float)id;
  }
  __syncthreads();
  #pragma unroll
  for (int i = 0; i < 16; ++i) {
    int li = t + i * 256, r = li >> 7, q = li & 127;
    *(float4*)(out + (size_t)(mBase + r) * DIM + q * 4) =
        *(const float4*)(cb + (size_t)idxs[r] * DIM + q * 4);
  }
}

extern "C" void kernel_launch(void* const* d_in, const int* in_sizes, int n_in,
                              void* d_out, int out_size, void* d_ws, size_t ws_size,
                              hipStream_t stream) {
  const float* z  = (const float*)d_in[0];
  const float* cb = (const float*)d_in[1];
  float* out = (float*)d_out;
  char* ws = (char*)d_ws;
  float*    pm1    = (float*)(ws + WS_PM1);
  unsigned* pix    = (unsigned*)(ws + WS_PIX);
  unsigned* pdl    = (unsigned*)(ws + WS_PDL);
  int*      fidx   = (int*)(ws + WS_FIDX);
  int*      pairM  = (int*)(ws + WS_PAIR);
  unsigned* pairIJ = (unsigned*)(ws + WS_PDL);   // reuse pdl region after k_merge? NO —
  // pdl is read only inside k_merge; pairIJ written by k_merge in the same launch.
  // Keep them separate for safety: pairIJ gets its own slot below.
  int*      deepL  = (int*)(ws + WS_DEEP);
  int*      cnts   = (int*)(ws + WS_CNT);
  float*    rdp    = (float*)(ws + WS_RD);   // overlays EH (dead after k_fastm)
  int*      rnp    = (int*)(ws + WS_RN);

  // pairIJ: use the second half of the PIX region (rows*4 u32 = 256 KB; pairIJ
  // needs <= NROWS u32 = 64 KB). PIX is dead after k_merge completes its reads —
  // but k_merge reads pix[m*4+s] and would write pairIJ concurrently. Avoid
  // aliasing entirely: place pairIJ in the PM1 region, which IS dead after
  // k_merge's reads... same concurrency issue. Use dedicated WS_PAIR+64KB? WS_PAIR
  // holds pairM (int[NROWS] = 64 KB at 851968..917504). WS_DEEP at 917504.
  // Free gap: none in control region. Solution: pairIJ goes to EH+2MB (dead).
  pairIJ = (unsigned*)(ws + WS_EH + 2097152);

  // z hi pre-split lives in d_out (16 MB <= out buffer); k_gather rewrites it.
  unsigned short* zh = (unsigned short*)d_out;
  unsigned short* eh = (unsigned short*)(ws + WS_EH);

  hipLaunchKernelGGL(k_presplit_h, dim3(NROWS * DIM / (256 * 8)), dim3(256), 0, stream,
                     z, zh);
  hipLaunchKernelGGL(k_presplit_h, dim3(NE * DIM / (256 * 8)), dim3(256), 0, stream,
                     cb, eh);
  hipLaunchKernelGGL(k_fastm,   dim3(NROWS / TMF, NSPLITF), dim3(256), 0, stream,
                     zh, eh, pm1, pix, pdl, cnts);
  hipLaunchKernelGGL(k_merge,   dim3(NROWS / 256), dim3(256), 0, stream,
                     z, pm1, pix, pdl, fidx, pairM, pairIJ, deepL, cnts);
  hipLaunchKernelGGL(k_pair,    dim3(NROWS / 256), dim3(256), 0, stream,
                     z, cb, pairM, pairIJ, cnts, fidx);
  hipLaunchKernelGGL(k_refine3, dim3(NROWS / RPB, NSR), dim3(256), 0, stream,
                     z, cb, deepL, cnts, rdp, rnp);
  hipLaunchKernelGGL(k_fmerge,  dim3(NROWS / 256), dim3(256), 0, stream,
                     deepL, cnts, rdp, rnp, fidx);
  hipLaunchKernelGGL(k_gather,  dim3(NROWS / 32), dim3(256), 0, stream,
                     cb, fidx, out);
}

// Round 17
// 753.076 us; speedup vs baseline: 2.0381x; 1.1010x over previous
//
#include <hip/hip_runtime.h>
#include <float.h>
#include <limits.h>

#define NROWS 16384
#define NE    8192
#define DIM   512

// ---- fast pass geometry ----
#define TMF 64
#define TNF 128
#define NSPLITF 4
#define NRANGE (NE / NSPLITF)   // 2048

// ---- refine geometry ----
#define RPB 8
#define NSR 8

// ---- quantization for stored gaps ----
#define DQSCALE 6.5536e7f       // u16 fixed-point (res 1.526e-8), floored -> conservative
#define DQINV   (1.0f / DQSCALE)

// ---- workspace layout (bytes); control region < 1 MB (EH at 1 MB) ----
#define WS_PM1  0               // float[NROWS*4]   m1 per (row,split)
#define WS_PIX  262144          // u32[NROWS*4]     i1 | i2<<13
#define WS_PDL  524288          // u32[NROWS*4]     dq2 | dq3<<16
#define WS_FIDX 786432          // int[NROWS]
#define WS_PAIR 851968          // int[NROWS]
#define WS_DEEP 917504          // int[NROWS]
#define WS_CNT  983040          // int[2]: pairCnt, deepCnt
#define WS_EH   1048576         // ushort[NE*DIM] = 8 MB (dead after k_fastm)
#define WS_RD   1048576         // float[deepCnt*NSR] overlays EH
#define WS_RN   1572864         // int[...]

typedef __bf16 bf16x8 __attribute__((ext_vector_type(8)));
typedef unsigned short u16x8 __attribute__((ext_vector_type(8)));
typedef float f32x4v __attribute__((ext_vector_type(4)));

__device__ __forceinline__ unsigned int bf16rne(float f) {
  unsigned int u = __float_as_uint(f);
  return (u + 0x7FFFu + ((u >> 16) & 1u)) >> 16;
}

typedef __attribute__((address_space(1))) const void GV;
typedef __attribute__((address_space(3))) void LV;
__device__ __forceinline__ void gload16(const void* g, void* l) {
  __builtin_amdgcn_global_load_lds((GV*)g, (LV*)l, 16, 0, 0);
}

// top-3 set merge (r13 proven): keeps first-index tie-break on m1.
__device__ __forceinline__ void merge3(float& am1, int& ai1, float& am2, int& ai2,
                                       float& am3, float bm1, int bi1, float bm2,
                                       int bi2, float bm3) {
  if (bm1 > am1 || (bm1 == am1 && bi1 < ai1)) {
    float t; int ti;
    t = am1; am1 = bm1; bm1 = t;  ti = ai1; ai1 = bi1; bi1 = ti;
    t = am2; am2 = bm2; bm2 = t;  ti = ai2; ai2 = bi2; bi2 = ti;
    t = am3; am3 = bm3; bm3 = t;
  }
  if (bm1 > am2) { am3 = fmaxf(am2, bm2); am2 = bm1; ai2 = bi1; }
  else           { am3 = fmaxf(am3, bm1); }
}

// ---------------- K0: elementwise bf16 hi-only pre-split ----------------
__global__ void k_presplit_h(const float* __restrict__ src,
                             unsigned short* __restrict__ hi) {
  size_t i8 = (size_t)blockIdx.x * 256 + threadIdx.x;
  const float4* s4 = (const float4*)src;
  float4 a = s4[i8 * 2], b = s4[i8 * 2 + 1];
  *(u16x8*)(hi + i8 * 8) = (u16x8){
      (unsigned short)bf16rne(a.x), (unsigned short)bf16rne(a.y),
      (unsigned short)bf16rne(a.z), (unsigned short)bf16rne(a.w),
      (unsigned short)bf16rne(b.x), (unsigned short)bf16rne(b.y),
      (unsigned short)bf16rne(b.z), (unsigned short)bf16rne(b.w)};
}

// ---------------- K1: 1-term bf16 MFMA GEMM-max + float/index top-3 ----------------
// grid (256,4), block 256 = 4 waves (2m x 2n), wave tile 32x64. r13 two-barrier
// structure; zh-only A, eh-only B (error absorbed by enlarged tau in k_merge).
__global__ __launch_bounds__(256, 2) void k_fastm(
    const unsigned short* __restrict__ zh, const unsigned short* __restrict__ eh,
    float* __restrict__ pm1, unsigned* __restrict__ pix, unsigned* __restrict__ pdl,
    int* __restrict__ counters) {
  __shared__ unsigned short zbuf[TMF][32];          //  4 KB single-buffered
  __shared__ unsigned short ebuf[2][TNF][32];       // 16 KB dbuf
  __shared__ float rm1[TMF][2], rm2[TMF][2], rm3[TMF][2];
  __shared__ int   ri1[TMF][2], ri2[TMF][2];

  const int t    = threadIdx.x;
  const int lane = t & 63, w = t >> 6;
  const int wm   = w >> 1, wn = w & 1;
  const int lr   = lane & 15, lg = lane >> 4;
  const int mBase  = blockIdx.x * TMF;
  const int nBase0 = blockIdx.y * NRANGE;
  if (blockIdx.x == 0 && blockIdx.y == 0 && t == 0) { counters[0] = 0; counters[1] = 0; }

  // staging lane maps (inverse-swizzled global source, linear LDS dest — rule #21)
  const int srz = (w << 4) + (lane >> 2);
  const unsigned zbase = (unsigned)(mBase + srz) * DIM + (((lane & 3) ^ ((srz >> 1) & 3)) << 3);
  const int sre0 = (w << 5) + (lane >> 2);
  const int sre1 = sre0 + 16;
  const unsigned ebase0 = (unsigned)(nBase0 + sre0) * DIM + (((lane & 3) ^ ((sre0 >> 1) & 3)) << 3);
  const unsigned ebase1 = (unsigned)(nBase0 + sre1) * DIM + (((lane & 3) ^ ((sre1 >> 1) & 3)) << 3);

  float m1[8], m2[8], m3[8]; int i1[8], i2[8];
  #pragma unroll
  for (int s = 0; s < 8; ++s) {
    m1[s] = -FLT_MAX; m2[s] = -FLT_MAX; m3[s] = -FLT_MAX;
    i1[s] = INT_MAX;  i2[s] = INT_MAX;
  }

  // prologue: stage step 0
  gload16(zh + zbase, &zbuf[w << 4][0]);
  gload16(eh + ebase0, &ebuf[0][w << 5][0]);
  gload16(eh + ebase1, &ebuf[0][(w << 5) + 16][0]);
  __syncthreads();

  int cur = 0;
  for (int nt = 0; nt < NRANGE / TNF; ++nt) {     // 16 n-tiles
    const int nB = nBase0 + nt * TNF;
    f32x4v acc[2][4];
    #pragma unroll
    for (int mi = 0; mi < 2; ++mi)
      #pragma unroll
      for (int nj = 0; nj < 4; ++nj) acc[mi][nj] = (f32x4v){0.f, 0.f, 0.f, 0.f};

    for (int ks = 0; ks < 16; ++ks) {             // 16 K-steps of 32
      // ---- a-frags from zbuf (swizzled reads) ----
      bf16x8 ah[2];
      #pragma unroll
      for (int mi = 0; mi < 2; ++mi) {
        int row = wm * 32 + mi * 16 + lr;
        int sl  = (lg ^ ((row >> 1) & 3)) * 8;
        ah[mi] = *(const bf16x8*)&zbuf[row][sl];
      }
      __syncthreads();   // A: a-frag reads retired; zbuf safe to overwrite

      // ---- stage next step (async; hides under MFMA) ----
      int s = nt * 16 + ks;
      if (s + 1 < 256) {
        int s2 = s + 1;
        unsigned zo = (unsigned)((s2 & 15) << 5);
        unsigned vo = ((unsigned)(s2 >> 4) << 16) | zo;   // nt2*TNF*DIM + ks2*32
        gload16(zh + zbase + zo, &zbuf[w << 4][0]);
        gload16(eh + ebase0 + vo, &ebuf[cur ^ 1][w << 5][0]);
        gload16(eh + ebase1 + vo, &ebuf[cur ^ 1][(w << 5) + 16][0]);
      }

      // ---- b-frags + 8 MFMA from ebuf[cur] ----
      #pragma unroll
      for (int nj = 0; nj < 4; ++nj) {
        int erow = wn * 64 + nj * 16 + lr;
        int esl  = (lg ^ ((erow >> 1) & 3)) * 8;
        bf16x8 bh = *(const bf16x8*)&ebuf[cur][erow][esl];
        #pragma unroll
        for (int mi = 0; mi < 2; ++mi)
          acc[mi][nj] = __builtin_amdgcn_mfma_f32_16x16x32_bf16(ah[mi], bh, acc[mi][nj], 0, 0, 0);
      }
      __syncthreads();   // B: drains vmcnt (stages landed) + lgkm (b reads done)
      cur ^= 1;
    }
    // fold into per-thread top-3 — m3-first fast path (identical semantics,
    // ~90% of values exit after one compare)
    #pragma unroll
    for (int nj = 0; nj < 4; ++nj) {
      int n = nB + wn * 64 + nj * 16 + lr;
      #pragma unroll
      for (int mi = 0; mi < 2; ++mi)
        #pragma unroll
        for (int r = 0; r < 4; ++r) {
          float v = acc[mi][nj][r];
          int s = mi * 4 + r;
          if (v > m3[s]) {
            if (v > m1[s]) { m3[s] = m2[s]; m2[s] = m1[s]; i2[s] = i1[s]; m1[s] = v; i1[s] = n; }
            else if (v > m2[s]) { m3[s] = m2[s]; m2[s] = v; i2[s] = n; }
            else { m3[s] = v; }
          }
        }
    }
  }

  // butterfly top-3 merge across the 16 col-lanes
  #pragma unroll
  for (int off = 1; off <= 8; off <<= 1) {
    #pragma unroll
    for (int s = 0; s < 8; ++s) {
      float om1 = __shfl_xor(m1[s], off);
      float om2 = __shfl_xor(m2[s], off);
      float om3 = __shfl_xor(m3[s], off);
      int   oi1 = __shfl_xor(i1[s], off);
      int   oi2 = __shfl_xor(i2[s], off);
      merge3(m1[s], i1[s], m2[s], i2[s], m3[s], om1, oi1, om2, oi2, om3);
    }
  }
  if (lr == 0) {
    #pragma unroll
    for (int s = 0; s < 8; ++s) {
      int row = wm * 32 + (s >> 2) * 16 + lg * 4 + (s & 3);
      rm1[row][wn] = m1[s]; rm2[row][wn] = m2[s]; rm3[row][wn] = m3[s];
      ri1[row][wn] = i1[s]; ri2[row][wn] = i2[s];
    }
  }
  __syncthreads();
  if (t < TMF) {
    float M1 = rm1[t][0], M2 = rm2[t][0], M3 = rm3[t][0];
    int   I1 = ri1[t][0], I2 = ri2[t][0];
    merge3(M1, I1, M2, I2, M3, rm1[t][1], ri1[t][1], rm2[t][1], ri2[t][1], rm3[t][1]);
    size_t gm = (size_t)(mBase + t) * NSPLITF + blockIdx.y;
    unsigned q2 = (unsigned)fminf((M1 - M2) * DQSCALE, 65535.0f);  // floored: underest.
    unsigned q3 = (unsigned)fminf((M1 - M3) * DQSCALE, 65535.0f);
    pm1[gm] = M1;
    pix[gm] = (unsigned)I1 | ((unsigned)I2 << 13);
    pdl[gm] = q2 | (q3 << 16);
  }
}

// ---------------- K2: merge splits, compute A, classify done/pair/deep ----------------
__global__ void k_merge(const float* __restrict__ z,
                        const float* __restrict__ pm1, const unsigned* __restrict__ pix,
                        const unsigned* __restrict__ pdl,
                        int* __restrict__ fidx, int* __restrict__ pairM,
                        unsigned* __restrict__ pairIJ, int* __restrict__ deepL,
                        int* __restrict__ counters) {
  int m = blockIdx.x * 256 + threadIdx.x;
  float M1 = -FLT_MAX, M2 = -FLT_MAX, M3 = -FLT_MAX; int I1 = INT_MAX, I2 = INT_MAX;
  #pragma unroll
  for (int s = 0; s < NSPLITF; ++s) {
    size_t g = (size_t)m * NSPLITF + s;
    float bm1 = pm1[g];
    unsigned ij = pix[g], dq = pdl[g];
    int   bi1 = (int)(ij & 8191u), bi2 = (int)((ij >> 13) & 8191u);
    float bm2 = bm1 - (float)(dq & 0xFFFFu) * DQINV;   // >= true m2 (conservative)
    float bm3 = bm1 - (float)(dq >> 16) * DQINV;
    merge3(M1, I1, M2, I2, M3, bm1, bi1, bm2, bi2, bm3);
  }
  double A = 0.0;
  const float4* zr = (const float4*)(z + (size_t)m * DIM);
  for (int q = 0; q < DIM / 4; ++q) {
    float4 v = zr[q];
    A += (double)v.x * v.x + (double)v.y * v.y + (double)v.z * v.z + (double)v.w * v.w;
  }
  float A32 = (float)A;
  // 1-term fast pass: estimate error sigma ~2.5e-6 (Bernstein: P(eta>2.6e-5)
  // ~3e-12/entry). unflagged needs tau > 0.5*ulp_d + 2*eta -> 0.75u + 4e-5 safe.
  float u   = (A32 > 511.8f) ? 6.1035156e-5f : 3.0517578e-5f;
  float tau = 0.75f * u + 4.0e-5f;
  fidx[m] = I1;
  if (M1 - M2 < tau) {
    if (M1 - M3 >= tau + 1.2e-5f) {      // guard: candidates provably {I1,I2}
      int p = atomicAdd(&counters[0], 1);
      pairM[p] = m;
      pairIJ[p] = (unsigned)I1 | ((unsigned)I2 << 13);
    } else {
      int p = atomicAdd(&counters[1], 1);
      deepL[p] = m;
    }
  }
}

// exact npyv (baseline-SSE) fp32 d for one (z-row, cb-row): verified chain (r2/r3)
__device__ float npyv_d(const float* __restrict__ zr, const float* __restrict__ er,
                        float A32) {
  float L0 = 0.f, L1 = 0.f, L2 = 0.f, L3 = 0.f;
  for (int c = 0; c < 32; ++c) {
    #pragma unroll
    for (int sub = 3; sub >= 0; --sub) {
      int base = c * 16 + sub * 4;
      float4 zv = *(const float4*)(zr + base);
      float4 ev = *(const float4*)(er + base);
      L0 = __fadd_rn(L0, __fmul_rn(zv.x, ev.x));
      L1 = __fadd_rn(L1, __fmul_rn(zv.y, ev.y));
      L2 = __fadd_rn(L2, __fmul_rn(zv.z, ev.z));
      L3 = __fadd_rn(L3, __fmul_rn(zv.w, ev.w));
    }
  }
  float G = __fadd_rn(__fadd_rn(L0, L1), __fadd_rn(L2, L3));
  return __fsub_rn(A32, __fmul_rn(2.0f, G));
}

// ---------------- K3a: pair refine (one thread per flagged-pair row) ----------------
__global__ void k_pair(const float* __restrict__ z, const float* __restrict__ cb,
                       const int* __restrict__ pairM, const unsigned* __restrict__ pairIJ,
                       const int* __restrict__ counters, int* __restrict__ fidx) {
  int i = blockIdx.x * 256 + threadIdx.x;
  if (i >= counters[0]) return;
  int m = pairM[i];
  unsigned ij = pairIJ[i];
  int iA = (int)(ij & 8191u), iB = (int)((ij >> 13) & 8191u);
  const float* zr = z + (size_t)m * DIM;
  double A = 0.0;
  for (int q = 0; q < DIM / 4; ++q) {
    float4 v = *(const float4*)(zr + q * 4);
    A += (double)v.x * v.x + (double)v.y * v.y + (double)v.z * v.z + (double)v.w * v.w;
  }
  float A32 = (float)A;
  float dA = npyv_d(zr, cb + (size_t)iA * DIM, A32);
  float dB = npyv_d(zr, cb + (size_t)iB * DIM, A32);
  fidx[m] = (dB < dA || (dB == dA && iB < iA)) ? iB : iA;
}

// ---------------- K3b: exact npyv full rescan for deep rows ----------------
__global__ __launch_bounds__(256) void k_refine3(
    const float* __restrict__ z, const float* __restrict__ cb,
    const int* __restrict__ deepL, const int* __restrict__ counters,
    float* __restrict__ rd, int* __restrict__ rn) {
  __shared__ float est2[512][20];
  __shared__ __align__(16) float zs2[RPB][516];
  __shared__ double apart[RPB][16];
  __shared__ float Arow[RPB];
  __shared__ int mrow[RPB];
  __shared__ float rdm[RPB][128];
  __shared__ int rnm[RPB][128];

  const int cnt = counters[1];
  const int gB = blockIdx.x * RPB;
  if (gB >= cnt) return;
  const int t = threadIdx.x;
  const int split = blockIdx.y;
  const int nBase0 = split * (NE / NSR);
  const int rg = t >> 7, cg = t & 127;

  if (t < RPB) mrow[t] = deepL[(gB + t < cnt) ? gB + t : cnt - 1];
  __syncthreads();
  #pragma unroll
  for (int i = 0; i < 4; ++i) {
    int li = t + 256 * i; int r = li >> 7, q = li & 127;
    *(float4*)&zs2[r][q * 4] = *(const float4*)(z + (size_t)mrow[r] * DIM + q * 4);
  }
  __syncthreads();
  if (t < 128) {
    int r = t >> 4, seg = t & 15;
    double s = 0.0;
    for (int k = seg * 32; k < seg * 32 + 32; ++k) { double v = zs2[r][k]; s += v * v; }
    apart[r][seg] = s;
  }
  __syncthreads();
  if (t < RPB) { double s = 0.0; for (int c2 = 0; c2 < 16; ++c2) s += apart[t][c2]; Arow[t] = (float)s; }
  __syncthreads();

  float bd[4] = {FLT_MAX, FLT_MAX, FLT_MAX, FLT_MAX};
  int   bn[4] = {INT_MAX, INT_MAX, INT_MAX, INT_MAX};

  for (int tile = 0; tile < 2; ++tile) {
    const int colBase = nBase0 + tile * 512;
    float L[4][4][4];
    #pragma unroll
    for (int r = 0; r < 4; ++r)
      #pragma unroll
      for (int cj = 0; cj < 4; ++cj)
        #pragma unroll
        for (int j = 0; j < 4; ++j) L[r][cj][j] = 0.0f;

    for (int kc = 0; kc < DIM; kc += 16) {
      __syncthreads();
      #pragma unroll
      for (int i = 0; i < 8; ++i) {
        int li = t + 256 * i; int col = li >> 2, q = li & 3;
        float4 v = *(const float4*)(cb + (size_t)(colBase + col) * DIM + kc + 4 * q);
        *(float4*)&est2[col][4 * q] = v;
      }
      __syncthreads();
      #pragma unroll
      for (int sub = 3; sub >= 0; --sub) {
        float4 zv[4], ev[4];
        #pragma unroll
        for (int r = 0; r < 4; ++r)
          zv[r] = *(const float4*)&zs2[rg * 4 + r][kc + 4 * sub];
        #pragma unroll
        for (int cj = 0; cj < 4; ++cj)
          ev[cj] = *(const float4*)&est2[cg + 128 * cj][4 * sub];
        #pragma unroll
        for (int r = 0; r < 4; ++r)
          #pragma unroll
          for (int cj = 0; cj < 4; ++cj) {
            L[r][cj][0] = __fadd_rn(L[r][cj][0], __fmul_rn(zv[r].x, ev[cj].x));
            L[r][cj][1] = __fadd_rn(L[r][cj][1], __fmul_rn(zv[r].y, ev[cj].y));
            L[r][cj][2] = __fadd_rn(L[r][cj][2], __fmul_rn(zv[r].z, ev[cj].z));
            L[r][cj][3] = __fadd_rn(L[r][cj][3], __fmul_rn(zv[r].w, ev[cj].w));
          }
      }
    }
    #pragma unroll
    for (int cj = 0; cj < 4; ++cj)
      #pragma unroll
      for (int r = 0; r < 4; ++r) {
        float G = __fadd_rn(__fadd_rn(L[r][cj][0], L[r][cj][1]),
                            __fadd_rn(L[r][cj][2], L[r][cj][3]));
        float d = __fsub_rn(Arow[rg * 4 + r], __fmul_rn(2.0f, G));
        int n = colBase + cg + 128 * cj;
        if (d < bd[r] || (d == bd[r] && n < bn[r])) { bd[r] = d; bn[r] = n; }
      }
  }
  __syncthreads();
  #pragma unroll
  for (int r = 0; r < 4; ++r) { rdm[rg*4+r][cg] = bd[r]; rnm[rg*4+r][cg] = bn[r]; }
  __syncthreads();
  if (t < RPB && gB + t < cnt) {
    float fb = FLT_MAX; int fn = INT_MAX;
    for (int c2 = 0; c2 < 128; ++c2) {
      float d = rdm[t][c2]; int n = rnm[t][c2];
      if (d < fb || (d == fb && n < fn)) { fb = d; fn = n; }
    }
    size_t i = (size_t)(gB + t);
    rd[i * NSR + split] = fb;
    rn[i * NSR + split] = fn;
  }
}

// ---------------- K3c: merge deep splits ----------------
__global__ void k_fmerge(const int* __restrict__ deepL, const int* __restrict__ counters,
                         const float* __restrict__ rd, const int* __restrict__ rn,
                         int* __restrict__ fidx) {
  int i = blockIdx.x * 256 + threadIdx.x;
  if (i >= counters[1]) return;
  int m = deepL[i];
  float fb = FLT_MAX; int fn = INT_MAX;
  #pragma unroll
  for (int s = 0; s < NSR; ++s) {
    float d = rd[(size_t)i * NSR + s]; int n = rn[(size_t)i * NSR + s];
    if (d < fb || (d == fb && n < fn)) { fb = d; fn = n; }
  }
  fidx[m] = fn;
}

// ---------------- K4: gather z_q + index floats (fully rewrites d_out) ----------------
__global__ void k_gather(const float* __restrict__ cb, const int* __restrict__ fidx,
                         float* __restrict__ out) {
  __shared__ int idxs[32];
  const int t = threadIdx.x;
  const int mBase = blockIdx.x * 32;
  if (t < 32) {
    int id = fidx[mBase + t];
    idxs[t] = id;
    out[(size_t)NROWS * DIM + mBase + t] = (float)id;
  }
  __syncthreads();
  #pragma unroll
  for (int i = 0; i < 16; ++i) {
    int li = t + i * 256, r = li >> 7, q = li & 127;
    *(float4*)(out + (size_t)(mBase + r) * DIM + q * 4) =
        *(const float4*)(cb + (size_t)idxs[r] * DIM + q * 4);
  }
}

extern "C" void kernel_launch(void* const* d_in, const int* in_sizes, int n_in,
                              void* d_out, int out_size, void* d_ws, size_t ws_size,
                              hipStream_t stream) {
  const float* z  = (const float*)d_in[0];
  const float* cb = (const float*)d_in[1];
  float* out = (float*)d_out;
  char* ws = (char*)d_ws;
  float*    pm1    = (float*)(ws + WS_PM1);
  unsigned* pix    = (unsigned*)(ws + WS_PIX);
  unsigned* pdl    = (unsigned*)(ws + WS_PDL);
  int*      fidx   = (int*)(ws + WS_FIDX);
  int*      pairM  = (int*)(ws + WS_PAIR);
  int*      deepL  = (int*)(ws + WS_DEEP);
  int*      cnts   = (int*)(ws + WS_CNT);
  float*    rdp    = (float*)(ws + WS_RD);   // overlays EH (dead after k_fastm)
  int*      rnp    = (int*)(ws + WS_RN);
  // pairIJ lives in the dead EH region +2MB (no control-region space, no aliasing)
  unsigned* pairIJ = (unsigned*)(ws + WS_EH + 2097152);

  // z hi pre-split lives in d_out (16 MB <= out buffer); k_gather rewrites it.
  unsigned short* zh = (unsigned short*)d_out;
  unsigned short* eh = (unsigned short*)(ws + WS_EH);

  hipLaunchKernelGGL(k_presplit_h, dim3(NROWS * DIM / (256 * 8)), dim3(256), 0, stream,
                     z, zh);
  hipLaunchKernelGGL(k_presplit_h, dim3(NE * DIM / (256 * 8)), dim3(256), 0, stream,
                     cb, eh);
  hipLaunchKernelGGL(k_fastm,   dim3(NROWS / TMF, NSPLITF), dim3(256), 0, stream,
                     zh, eh, pm1, pix, pdl, cnts);
  hipLaunchKernelGGL(k_merge,   dim3(NROWS / 256), dim3(256), 0, stream,
                     z, pm1, pix, pdl, fidx, pairM, pairIJ, deepL, cnts);
  hipLaunchKernelGGL(k_pair,    dim3(NROWS / 256), dim3(256), 0, stream,
                     z, cb, pairM, pairIJ, cnts, fidx);
  hipLaunchKernelGGL(k_refine3, dim3(NROWS / RPB, NSR), dim3(256), 0, stream,
                     z, cb, deepL, cnts, rdp, rnp);
  hipLaunchKernelGGL(k_fmerge,  dim3(NROWS / 256), dim3(256), 0, stream,
                     deepL, cnts, rdp, rnp, fidx);
  hipLaunchKernelGGL(k_gather,  dim3(NROWS / 32), dim3(256), 0, stream,
                     cb, fidx, out);
}

// Round 18
// 698.223 us; speedup vs baseline: 2.1982x; 1.0786x over previous
//
#include <hip/hip_runtime.h>
#include <float.h>
#include <limits.h>

#define NROWS 16384
#define NE    8192
#define DIM   512

// ---- fast pass geometry ----
#define TMF 64
#define TNF 128
#define NSPLITF 4
#define NRANGE (NE / NSPLITF)   // 2048

// ---- refine geometry ----
#define RPB 8
#define NSR 16

// ---- quantization for stored gaps ----
#define DQSCALE 6.5536e7f       // u16 fixed-point (res 1.526e-8), floored -> conservative
#define DQINV   (1.0f / DQSCALE)

// ---- workspace layout (bytes); control region < 1 MB (EH at 1 MB) ----
#define WS_PM1  0               // float[NROWS*4]   m1 per (row,split)
#define WS_PIX  262144          // u32[NROWS*4]     i1 | i2<<13
#define WS_PDL  524288          // u32[NROWS*4]     dq2 | dq3<<16
#define WS_FIDX 786432          // int[NROWS]
#define WS_PAIR 851968          // int[NROWS]
#define WS_DEEP 917504          // int[NROWS]
#define WS_CNT  983040          // int[2]: pairCnt, deepCnt
#define WS_EH   1048576         // ushort[NE*DIM] = 8 MB (dead after k_fastm)
#define WS_RD   1048576         // float[cnt*NSR] overlays EH   (1 MB)
#define WS_RN   2097152         // int[cnt*NSR]                 (1 MB)
#define WS_PIJ  3145728         // u32[NROWS] pairIJ            (64 KB)

typedef __bf16 bf16x8 __attribute__((ext_vector_type(8)));
typedef unsigned short u16x8 __attribute__((ext_vector_type(8)));
typedef float f32x4v __attribute__((ext_vector_type(4)));

__device__ __forceinline__ unsigned int bf16rne(float f) {
  unsigned int u = __float_as_uint(f);
  return (u + 0x7FFFu + ((u >> 16) & 1u)) >> 16;
}

typedef __attribute__((address_space(1))) const void GV;
typedef __attribute__((address_space(3))) void LV;
__device__ __forceinline__ void gload16(const void* g, void* l) {
  __builtin_amdgcn_global_load_lds((GV*)g, (LV*)l, 16, 0, 0);
}

// top-3 set merge (r13 proven): keeps first-index tie-break on m1.
__device__ __forceinline__ void merge3(float& am1, int& ai1, float& am2, int& ai2,
                                       float& am3, float bm1, int bi1, float bm2,
                                       int bi2, float bm3) {
  if (bm1 > am1 || (bm1 == am1 && bi1 < ai1)) {
    float t; int ti;
    t = am1; am1 = bm1; bm1 = t;  ti = ai1; ai1 = bi1; bi1 = ti;
    t = am2; am2 = bm2; bm2 = t;  ti = ai2; ai2 = bi2; bi2 = ti;
    t = am3; am3 = bm3; bm3 = t;
  }
  if (bm1 > am2) { am3 = fmaxf(am2, bm2); am2 = bm1; ai2 = bi1; }
  else           { am3 = fmaxf(am3, bm1); }
}

// ---------------- K0: elementwise bf16 hi-only pre-split ----------------
__global__ void k_presplit_h(const float* __restrict__ src,
                             unsigned short* __restrict__ hi) {
  size_t i8 = (size_t)blockIdx.x * 256 + threadIdx.x;
  const float4* s4 = (const float4*)src;
  float4 a = s4[i8 * 2], b = s4[i8 * 2 + 1];
  *(u16x8*)(hi + i8 * 8) = (u16x8){
      (unsigned short)bf16rne(a.x), (unsigned short)bf16rne(a.y),
      (unsigned short)bf16rne(a.z), (unsigned short)bf16rne(a.w),
      (unsigned short)bf16rne(b.x), (unsigned short)bf16rne(b.y),
      (unsigned short)bf16rne(b.z), (unsigned short)bf16rne(b.w)};
}

// ---------------- K1: 1-term bf16 MFMA GEMM-max, 2-ahead counted-vmcnt pipeline ----
// grid (256,4), block 256 = 4 waves (2m x 2n), wave tile 32x64.
// Triple-buffered z+e; stage step s+2 each iter; sync = s_waitcnt vmcnt(3) + raw
// s_barrier (T3/T4): only waits for loads issued TWO steps ago -> no drain stall.
__global__ __launch_bounds__(256, 2) void k_fastm(
    const unsigned short* __restrict__ zh, const unsigned short* __restrict__ eh,
    float* __restrict__ pm1, unsigned* __restrict__ pix, unsigned* __restrict__ pdl,
    int* __restrict__ counters) {
  __shared__ unsigned short zbuf[3][TMF][32];       // 12 KB
  __shared__ unsigned short ebuf[3][TNF][32];       // 24 KB
  __shared__ float rm1[TMF][2], rm2[TMF][2], rm3[TMF][2];
  __shared__ int   ri1[TMF][2], ri2[TMF][2];

  const int t    = threadIdx.x;
  const int lane = t & 63, w = t >> 6;
  const int wm   = w >> 1, wn = w & 1;
  const int lr   = lane & 15, lg = lane >> 4;
  const int mBase  = blockIdx.x * TMF;
  const int nBase0 = blockIdx.y * NRANGE;
  if (blockIdx.x == 0 && blockIdx.y == 0 && t == 0) { counters[0] = 0; counters[1] = 0; }

  // staging lane maps (inverse-swizzled global source, linear LDS dest — rule #21)
  const int srz = (w << 4) + (lane >> 2);
  const unsigned zbase = (unsigned)(mBase + srz) * DIM + (((lane & 3) ^ ((srz >> 1) & 3)) << 3);
  const int sre0 = (w << 5) + (lane >> 2);
  const int sre1 = sre0 + 16;
  const unsigned ebase0 = (unsigned)(nBase0 + sre0) * DIM + (((lane & 3) ^ ((sre0 >> 1) & 3)) << 3);
  const unsigned ebase1 = (unsigned)(nBase0 + sre1) * DIM + (((lane & 3) ^ ((sre1 >> 1) & 3)) << 3);

  float m1[8], m2[8], m3[8]; int i1[8], i2[8];
  #pragma unroll
  for (int s = 0; s < 8; ++s) {
    m1[s] = -FLT_MAX; m2[s] = -FLT_MAX; m3[s] = -FLT_MAX;
    i1[s] = INT_MAX;  i2[s] = INT_MAX;
  }

  // prologue: stage steps 0 and 1; wait only for step 0 (oldest 3 of 6)
  {
    gload16(zh + zbase, &zbuf[0][w << 4][0]);
    gload16(eh + ebase0, &ebuf[0][w << 5][0]);
    gload16(eh + ebase1, &ebuf[0][(w << 5) + 16][0]);
    unsigned zo1 = 32u, vo1 = 32u;               // s=1: ks2=1 -> offset 32 elems
    gload16(zh + zbase + zo1, &zbuf[1][w << 4][0]);
    gload16(eh + ebase0 + vo1, &ebuf[1][w << 5][0]);
    gload16(eh + ebase1 + vo1, &ebuf[1][(w << 5) + 16][0]);
  }
  asm volatile("s_waitcnt vmcnt(3)" ::: "memory");
  __builtin_amdgcn_s_barrier();

  int cur = 0;
  for (int nt = 0; nt < NRANGE / TNF; ++nt) {     // 16 n-tiles
    const int nB = nBase0 + nt * TNF;
    f32x4v acc[2][4];
    #pragma unroll
    for (int mi = 0; mi < 2; ++mi)
      #pragma unroll
      for (int nj = 0; nj < 4; ++nj) acc[mi][nj] = (f32x4v){0.f, 0.f, 0.f, 0.f};

    for (int ks = 0; ks < 16; ++ks) {             // 16 K-steps of 32
      int s = nt * 16 + ks;
      // ---- stage step s+2 into buf[(s+2)%3] (2-ahead; hides full latency) ----
      if (s + 2 < 256) {
        int s2 = s + 2;
        int st = cur >= 1 ? cur - 1 : cur + 2;    // (s+2)%3 = (cur+2)%3
        unsigned zo = (unsigned)((s2 & 15) << 5);
        unsigned vo = ((unsigned)(s2 >> 4) << 16) | zo;   // nt2*TNF*DIM + ks2*32
        gload16(zh + zbase + zo, &zbuf[st][w << 4][0]);
        gload16(eh + ebase0 + vo, &ebuf[st][w << 5][0]);
        gload16(eh + ebase1 + vo, &ebuf[st][(w << 5) + 16][0]);
      }
      // ---- a-frags + b-frags + 8 MFMA from buf[cur] (swizzled reads) ----
      bf16x8 ah[2];
      #pragma unroll
      for (int mi = 0; mi < 2; ++mi) {
        int row = wm * 32 + mi * 16 + lr;
        int sl  = (lg ^ ((row >> 1) & 3)) * 8;
        ah[mi] = *(const bf16x8*)&zbuf[cur][row][sl];
      }
      #pragma unroll
      for (int nj = 0; nj < 4; ++nj) {
        int erow = wn * 64 + nj * 16 + lr;
        int esl  = (lg ^ ((erow >> 1) & 3)) * 8;
        bf16x8 bh = *(const bf16x8*)&ebuf[cur][erow][esl];
        #pragma unroll
        for (int mi = 0; mi < 2; ++mi)
          acc[mi][nj] = __builtin_amdgcn_mfma_f32_16x16x32_bf16(ah[mi], bh, acc[mi][nj], 0, 0, 0);
      }
      // ---- counted sync: need stage(s+1) done; allow stage(s+2)'s 3 in flight ----
      if (s < 254) asm volatile("s_waitcnt vmcnt(3)" ::: "memory");
      else         asm volatile("s_waitcnt vmcnt(0)" ::: "memory");
      __builtin_amdgcn_s_barrier();
      cur = cur < 2 ? cur + 1 : 0;
    }
    // fold into per-thread top-3 (r16 order; n ascending -> first index kept)
    #pragma unroll
    for (int nj = 0; nj < 4; ++nj) {
      int n = nB + wn * 64 + nj * 16 + lr;
      #pragma unroll
      for (int mi = 0; mi < 2; ++mi)
        #pragma unroll
        for (int r = 0; r < 4; ++r) {
          float v = acc[mi][nj][r];
          int s = mi * 4 + r;
          if (v > m1[s]) { m3[s] = m2[s]; m2[s] = m1[s]; i2[s] = i1[s]; m1[s] = v; i1[s] = n; }
          else if (v > m2[s]) { m3[s] = m2[s]; m2[s] = v; i2[s] = n; }
          else if (v > m3[s]) { m3[s] = v; }
        }
    }
  }

  // butterfly top-3 merge across the 16 col-lanes
  #pragma unroll
  for (int off = 1; off <= 8; off <<= 1) {
    #pragma unroll
    for (int s = 0; s < 8; ++s) {
      float om1 = __shfl_xor(m1[s], off);
      float om2 = __shfl_xor(m2[s], off);
      float om3 = __shfl_xor(m3[s], off);
      int   oi1 = __shfl_xor(i1[s], off);
      int   oi2 = __shfl_xor(i2[s], off);
      merge3(m1[s], i1[s], m2[s], i2[s], m3[s], om1, oi1, om2, oi2, om3);
    }
  }
  if (lr == 0) {
    #pragma unroll
    for (int s = 0; s < 8; ++s) {
      int row = wm * 32 + (s >> 2) * 16 + lg * 4 + (s & 3);
      rm1[row][wn] = m1[s]; rm2[row][wn] = m2[s]; rm3[row][wn] = m3[s];
      ri1[row][wn] = i1[s]; ri2[row][wn] = i2[s];
    }
  }
  __syncthreads();
  if (t < TMF) {
    float M1 = rm1[t][0], M2 = rm2[t][0], M3 = rm3[t][0];
    int   I1 = ri1[t][0], I2 = ri2[t][0];
    merge3(M1, I1, M2, I2, M3, rm1[t][1], ri1[t][1], rm2[t][1], ri2[t][1], rm3[t][1]);
    size_t gm = (size_t)(mBase + t) * NSPLITF + blockIdx.y;
    unsigned q2 = (unsigned)fminf((M1 - M2) * DQSCALE, 65535.0f);  // floored: underest.
    unsigned q3 = (unsigned)fminf((M1 - M3) * DQSCALE, 65535.0f);
    pm1[gm] = M1;
    pix[gm] = (unsigned)I1 | ((unsigned)I2 << 13);
    pdl[gm] = q2 | (q3 << 16);
  }
}

// ---------------- K2: merge splits, compute A, classify done/pair/deep ----------------
__global__ void k_merge(const float* __restrict__ z,
                        const float* __restrict__ pm1, const unsigned* __restrict__ pix,
                        const unsigned* __restrict__ pdl,
                        int* __restrict__ fidx, int* __restrict__ pairM,
                        unsigned* __restrict__ pairIJ, int* __restrict__ deepL,
                        int* __restrict__ counters) {
  int m = blockIdx.x * 256 + threadIdx.x;
  float M1 = -FLT_MAX, M2 = -FLT_MAX, M3 = -FLT_MAX; int I1 = INT_MAX, I2 = INT_MAX;
  #pragma unroll
  for (int s = 0; s < NSPLITF; ++s) {
    size_t g = (size_t)m * NSPLITF + s;
    float bm1 = pm1[g];
    unsigned ij = pix[g], dq = pdl[g];
    int   bi1 = (int)(ij & 8191u), bi2 = (int)((ij >> 13) & 8191u);
    float bm2 = bm1 - (float)(dq & 0xFFFFu) * DQINV;   // >= true m2 (conservative)
    float bm3 = bm1 - (float)(dq >> 16) * DQINV;
    merge3(M1, I1, M2, I2, M3, bm1, bi1, bm2, bi2, bm3);
  }
  double A = 0.0;
  const float4* zr = (const float4*)(z + (size_t)m * DIM);
  for (int q = 0; q < DIM / 4; ++q) {
    float4 v = zr[q];
    A += (double)v.x * v.x + (double)v.y * v.y + (double)v.z * v.z + (double)v.w * v.w;
  }
  float A32 = (float)A;
  // 1-term fast pass: estimate error sigma ~2.5e-6 (Bernstein: P(eta>2.6e-5)
  // ~3e-12/entry). unflagged needs tau > 0.5*ulp_d + 2*eta -> 0.75u + 4e-5 safe.
  float u   = (A32 > 511.8f) ? 6.1035156e-5f : 3.0517578e-5f;
  float tau = 0.75f * u + 4.0e-5f;
  fidx[m] = I1;
  if (M1 - M2 < tau) {
    if (M1 - M3 >= tau + 1.2e-5f) {      // guard: candidates provably {I1,I2}
      int p = atomicAdd(&counters[0], 1);
      pairM[p] = m;
      pairIJ[p] = (unsigned)I1 | ((unsigned)I2 << 13);
    } else {
      int p = atomicAdd(&counters[1], 1);
      deepL[p] = m;
    }
  }
}

// exact npyv (baseline-SSE) fp32 d for one (z-row, cb-row): verified chain (r2/r3)
__device__ float npyv_d(const float* __restrict__ zr, const float* __restrict__ er,
                        float A32) {
  float L0 = 0.f, L1 = 0.f, L2 = 0.f, L3 = 0.f;
  for (int c = 0; c < 32; ++c) {
    #pragma unroll
    for (int sub = 3; sub >= 0; --sub) {
      int base = c * 16 + sub * 4;
      float4 zv = *(const float4*)(zr + base);
      float4 ev = *(const float4*)(er + base);
      L0 = __fadd_rn(L0, __fmul_rn(zv.x, ev.x));
      L1 = __fadd_rn(L1, __fmul_rn(zv.y, ev.y));
      L2 = __fadd_rn(L2, __fmul_rn(zv.z, ev.z));
      L3 = __fadd_rn(L3, __fmul_rn(zv.w, ev.w));
    }
  }
  float G = __fadd_rn(__fadd_rn(L0, L1), __fadd_rn(L2, L3));
  return __fsub_rn(A32, __fmul_rn(2.0f, G));
}

// ---------------- K3a: pair refine (one thread per flagged-pair row) ----------------
__global__ void k_pair(const float* __restrict__ z, const float* __restrict__ cb,
                       const int* __restrict__ pairM, const unsigned* __restrict__ pairIJ,
                       const int* __restrict__ counters, int* __restrict__ fidx) {
  int i = blockIdx.x * 256 + threadIdx.x;
  if (i >= counters[0]) return;
  int m = pairM[i];
  unsigned ij = pairIJ[i];
  int iA = (int)(ij & 8191u), iB = (int)((ij >> 13) & 8191u);
  const float* zr = z + (size_t)m * DIM;
  double A = 0.0;
  for (int q = 0; q < DIM / 4; ++q) {
    float4 v = *(const float4*)(zr + q * 4);
    A += (double)v.x * v.x + (double)v.y * v.y + (double)v.z * v.z + (double)v.w * v.w;
  }
  float A32 = (float)A;
  float dA = npyv_d(zr, cb + (size_t)iA * DIM, A32);
  float dB = npyv_d(zr, cb + (size_t)iB * DIM, A32);
  fidx[m] = (dB < dA || (dB == dA && iB < iA)) ? iB : iA;
}

// ---------------- K3b: exact npyv rescan for deep rows (16 n-splits of 512) ----------
__global__ __launch_bounds__(256) void k_refine3(
    const float* __restrict__ z, const float* __restrict__ cb,
    const int* __restrict__ deepL, const int* __restrict__ counters,
    float* __restrict__ rd, int* __restrict__ rn) {
  __shared__ float est2[512][20];
  __shared__ __align__(16) float zs2[RPB][516];
  __shared__ double apart[RPB][16];
  __shared__ float Arow[RPB];
  __shared__ int mrow[RPB];
  __shared__ float rdm[RPB][128];
  __shared__ int rnm[RPB][128];

  const int cnt = counters[1];
  const int gB = blockIdx.x * RPB;
  if (gB >= cnt) return;
  const int t = threadIdx.x;
  const int split = blockIdx.y;
  const int colBase = split * (NE / NSR);          // 512-col range
  const int rg = t >> 7, cg = t & 127;

  if (t < RPB) mrow[t] = deepL[(gB + t < cnt) ? gB + t : cnt - 1];
  __syncthreads();
  #pragma unroll
  for (int i = 0; i < 4; ++i) {
    int li = t + 256 * i; int r = li >> 7, q = li & 127;
    *(float4*)&zs2[r][q * 4] = *(const float4*)(z + (size_t)mrow[r] * DIM + q * 4);
  }
  __syncthreads();
  if (t < 128) {
    int r = t >> 4, seg = t & 15;
    double s = 0.0;
    for (int k = seg * 32; k < seg * 32 + 32; ++k) { double v = zs2[r][k]; s += v * v; }
    apart[r][seg] = s;
  }
  __syncthreads();
  if (t < RPB) { double s = 0.0; for (int c2 = 0; c2 < 16; ++c2) s += apart[t][c2]; Arow[t] = (float)s; }
  __syncthreads();

  float bd[4] = {FLT_MAX, FLT_MAX, FLT_MAX, FLT_MAX};
  int   bn[4] = {INT_MAX, INT_MAX, INT_MAX, INT_MAX};

  {
    float L[4][4][4];
    #pragma unroll
    for (int r = 0; r < 4; ++r)
      #pragma unroll
      for (int cj = 0; cj < 4; ++cj)
        #pragma unroll
        for (int j = 0; j < 4; ++j) L[r][cj][j] = 0.0f;

    for (int kc = 0; kc < DIM; kc += 16) {
      __syncthreads();
      #pragma unroll
      for (int i = 0; i < 8; ++i) {
        int li = t + 256 * i; int col = li >> 2, q = li & 3;
        float4 v = *(const float4*)(cb + (size_t)(colBase + col) * DIM + kc + 4 * q);
        *(float4*)&est2[col][4 * q] = v;
      }
      __syncthreads();
      #pragma unroll
      for (int sub = 3; sub >= 0; --sub) {
        float4 zv[4], ev[4];
        #pragma unroll
        for (int r = 0; r < 4; ++r)
          zv[r] = *(const float4*)&zs2[rg * 4 + r][kc + 4 * sub];
        #pragma unroll
        for (int cj = 0; cj < 4; ++cj)
          ev[cj] = *(const float4*)&est2[cg + 128 * cj][4 * sub];
        #pragma unroll
        for (int r = 0; r < 4; ++r)
          #pragma unroll
          for (int cj = 0; cj < 4; ++cj) {
            L[r][cj][0] = __fadd_rn(L[r][cj][0], __fmul_rn(zv[r].x, ev[cj].x));
            L[r][cj][1] = __fadd_rn(L[r][cj][1], __fmul_rn(zv[r].y, ev[cj].y));
            L[r][cj][2] = __fadd_rn(L[r][cj][2], __fmul_rn(zv[r].z, ev[cj].z));
            L[r][cj][3] = __fadd_rn(L[r][cj][3], __fmul_rn(zv[r].w, ev[cj].w));
          }
      }
    }
    #pragma unroll
    for (int cj = 0; cj < 4; ++cj)
      #pragma unroll
      for (int r = 0; r < 4; ++r) {
        float G = __fadd_rn(__fadd_rn(L[r][cj][0], L[r][cj][1]),
                            __fadd_rn(L[r][cj][2], L[r][cj][3]));
        float d = __fsub_rn(Arow[rg * 4 + r], __fmul_rn(2.0f, G));
        int n = colBase + cg + 128 * cj;
        if (d < bd[r] || (d == bd[r] && n < bn[r])) { bd[r] = d; bn[r] = n; }
      }
  }
  __syncthreads();
  #pragma unroll
  for (int r = 0; r < 4; ++r) { rdm[rg*4+r][cg] = bd[r]; rnm[rg*4+r][cg] = bn[r]; }
  __syncthreads();
  if (t < RPB && gB + t < cnt) {
    float fb = FLT_MAX; int fn = INT_MAX;
    for (int c2 = 0; c2 < 128; ++c2) {
      float d = rdm[t][c2]; int n = rnm[t][c2];
      if (d < fb || (d == fb && n < fn)) { fb = d; fn = n; }
    }
    size_t i = (size_t)(gB + t);
    rd[i * NSR + split] = fb;
    rn[i * NSR + split] = fn;
  }
}

// ---------------- K3c: merge deep splits ----------------
__global__ void k_fmerge(const int* __restrict__ deepL, const int* __restrict__ counters,
                         const float* __restrict__ rd, const int* __restrict__ rn,
                         int* __restrict__ fidx) {
  int i = blockIdx.x * 256 + threadIdx.x;
  if (i >= counters[1]) return;
  int m = deepL[i];
  float fb = FLT_MAX; int fn = INT_MAX;
  #pragma unroll
  for (int s = 0; s < NSR; ++s) {
    float d = rd[(size_t)i * NSR + s]; int n = rn[(size_t)i * NSR + s];
    if (d < fb || (d == fb && n < fn)) { fb = d; fn = n; }
  }
  fidx[m] = fn;
}

// ---------------- K4: gather z_q + index floats (fully rewrites d_out) ----------------
__global__ void k_gather(const float* __restrict__ cb, const int* __restrict__ fidx,
                         float* __restrict__ out) {
  __shared__ int idxs[32];
  const int t = threadIdx.x;
  const int mBase = blockIdx.x * 32;
  if (t < 32) {
    int id = fidx[mBase + t];
    idxs[t] = id;
    out[(size_t)NROWS * DIM + mBase + t] = (float)id;
  }
  __syncthreads();
  #pragma unroll
  for (int i = 0; i < 16; ++i) {
    int li = t + i * 256, r = li >> 7, q = li & 127;
    *(float4*)(out + (size_t)(mBase + r) * DIM + q * 4) =
        *(const float4*)(cb + (size_t)idxs[r] * DIM + q * 4);
  }
}

extern "C" void kernel_launch(void* const* d_in, const int* in_sizes, int n_in,
                              void* d_out, int out_size, void* d_ws, size_t ws_size,
                              hipStream_t stream) {
  const float* z  = (const float*)d_in[0];
  const float* cb = (const float*)d_in[1];
  float* out = (float*)d_out;
  char* ws = (char*)d_ws;
  float*    pm1    = (float*)(ws + WS_PM1);
  unsigned* pix    = (unsigned*)(ws + WS_PIX);
  unsigned* pdl    = (unsigned*)(ws + WS_PDL);
  int*      fidx   = (int*)(ws + WS_FIDX);
  int*      pairM  = (int*)(ws + WS_PAIR);
  int*      deepL  = (int*)(ws + WS_DEEP);
  int*      cnts   = (int*)(ws + WS_CNT);
  float*    rdp    = (float*)(ws + WS_RD);   // overlays EH (dead after k_fastm)
  int*      rnp    = (int*)(ws + WS_RN);
  unsigned* pairIJ = (unsigned*)(ws + WS_PIJ);

  // z hi pre-split lives in d_out (16 MB <= out buffer); k_gather rewrites it.
  unsigned short* zh = (unsigned short*)d_out;
  unsigned short* eh = (unsigned short*)(ws + WS_EH);

  hipLaunchKernelGGL(k_presplit_h, dim3(NROWS * DIM / (256 * 8)), dim3(256), 0, stream,
                     z, zh);
  hipLaunchKernelGGL(k_presplit_h, dim3(NE * DIM / (256 * 8)), dim3(256), 0, stream,
                     cb, eh);
  hipLaunchKernelGGL(k_fastm,   dim3(NROWS / TMF, NSPLITF), dim3(256), 0, stream,
                     zh, eh, pm1, pix, pdl, cnts);
  hipLaunchKernelGGL(k_merge,   dim3(NROWS / 256), dim3(256), 0, stream,
                     z, pm1, pix, pdl, fidx, pairM, pairIJ, deepL, cnts);
  hipLaunchKernelGGL(k_pair,    dim3(NROWS / 256), dim3(256), 0, stream,
                     z, cb, pairM, pairIJ, cnts, fidx);
  hipLaunchKernelGGL(k_refine3, dim3(NROWS / RPB, NSR), dim3(256), 0, stream,
                     z, cb, deepL, cnts, rdp, rnp);
  hipLaunchKernelGGL(k_fmerge,  dim3(NROWS / 256), dim3(256), 0, stream,
                     deepL, cnts, rdp, rnp, fidx);
  hipLaunchKernelGGL(k_gather,  dim3(NROWS / 32), dim3(256), 0, stream,
                     cb, fidx, out);
}